// Round 9
// baseline (57304.608 us; speedup 1.0000x reference)
//
#include <hip/hip_runtime.h>
#include <cstdint>
#include <cstddef>

// TransitionDown: FPS(8192 of 32768) + 16-NN + (Linear 64->128, BN, ReLU) + gather/maxpool
// R9: single-WAVE FPS (64 threads) — no __syncthreads anywhere in the hot loop.
// Lane L owns cells 8L..8L+7 (bboxes in registers, statically indexed);
// md + segmax/arg + cstart in LDS; points packed float4(x,y,z,bitcast(oi)).
// FROZEN numerics (R5-PASS): d = fmaf(dz,dz,fmaf(dy,dy,dx*dx)) with __fsub_rn subs;
// fminf(old,d); kNN dot fma-asc + qq/pp fma chains; ties -> lowest original index
// (packed key (oi<<16)|spos, oi unique => identical ordering).

#define TD_N 32768
#define TD_M 8192

__device__ __forceinline__ float sq3_fma(float a, float b, float c) {
  return fmaf(c, c, fmaf(b, b, __fmul_rn(a, a)));
}

__device__ __forceinline__ int cell_of(float x, float y, float z) {
  int ix = min(7, (int)(x * 8.0f));
  int iy = min(7, (int)(y * 8.0f));
  int iz = min(7, (int)(z * 8.0f));
  return (iz << 6) | (iy << 3) | ix;
}

// ---------------- K0: AoS -> SoA + |p|^2 (fma chain) ----------------
__global__ void k_soa(const float* __restrict__ p1, float* __restrict__ px,
                      float* __restrict__ py, float* __restrict__ pz,
                      float* __restrict__ pp) {
  int i = blockIdx.x * 256 + threadIdx.x;
  float a = p1[i * 3 + 0], b = p1[i * 3 + 1], c = p1[i * 3 + 2];
  px[i] = a; py[i] = b; pz[i] = c;
  pp[i] = sq3_fma(a, b, c);
}

// ---------------- K0b: histogram + prefix -> cell_start, cursor ----------------
__global__ __launch_bounds__(1024) void k_cells(const float* __restrict__ px,
                                                const float* __restrict__ py,
                                                const float* __restrict__ pz,
                                                int* __restrict__ cstart,
                                                int* __restrict__ cursor) {
  __shared__ int hist[512];
  __shared__ int wsum[16];
  int t = threadIdx.x;
  if (t < 512) hist[t] = 0;
  __syncthreads();
  for (int i = t; i < TD_N; i += 1024)
    atomicAdd(&hist[cell_of(px[i], py[i], pz[i])], 1);
  __syncthreads();
  int v = (t < 512) ? hist[t] : 0;
  int lane = t & 63, w = t >> 6;
  int s = v;
#pragma unroll
  for (int off = 1; off < 64; off <<= 1) {
    int o = __shfl_up(s, off);
    if (lane >= off) s += o;
  }
  if (lane == 63) wsum[w] = s;
  __syncthreads();
  if (t == 0) { int a = 0; for (int i = 0; i < 16; ++i) { int x = wsum[i]; wsum[i] = a; a += x; } }
  __syncthreads();
  int ex = s - v + wsum[w];
  if (t < 512) { cstart[t] = ex; cursor[t] = ex; }
  if (t == 0) cstart[512] = TD_N;
}

// ---------------- K0c: scatter into cell-sorted packed float4 ----------------
// Atomic order nondeterministic, but FPS outputs are order-invariant (elementwise
// min_d updates + unique-original-index tie-breaks).
__global__ __launch_bounds__(256) void k_scatter(const float* __restrict__ px,
                                                 const float* __restrict__ py,
                                                 const float* __restrict__ pz,
                                                 int* __restrict__ cursor,
                                                 float4* __restrict__ pk) {
  int i = blockIdx.x * 256 + threadIdx.x;
  float X = px[i], Y = py[i], Z = pz[i];
  int c = cell_of(X, Y, Z);
  int pos = atomicAdd(&cursor[c], 1);
  pk[pos] = make_float4(X, Y, Z, __int_as_float(i));
}

// ---------------- K1: h = x@W + b, + per-block BN partial sums ----------------
__global__ __launch_bounds__(256) void k_mlp(const float* __restrict__ x,
                                             const float* __restrict__ W,
                                             const float* __restrict__ bias,
                                             float* __restrict__ h,
                                             float* __restrict__ part) {
  __shared__ float Wl[64 * 128];
  __shared__ float pl[4][2][128];
  int t = threadIdx.x;
#pragma unroll
  for (int i = 0; i < 8; ++i) {
    int f4 = t + i * 256;
    ((float4*)Wl)[f4] = ((const float4*)W)[f4];
  }
  __syncthreads();

  int rg = t >> 4;
  int ch = (t & 15) * 8;
  int row0 = blockIdx.x * 64 + rg * 4;

  float acc[4][8];
#pragma unroll
  for (int r = 0; r < 4; ++r)
#pragma unroll
    for (int c = 0; c < 8; ++c) acc[r][c] = 0.f;

  const float* xrow = x + (size_t)row0 * 64;
#pragma unroll 4
  for (int kc = 0; kc < 16; ++kc) {
    float xv[4][4];
#pragma unroll
    for (int r = 0; r < 4; ++r) {
      float4 t4 = *(const float4*)(xrow + r * 64 + kc * 4);
      xv[r][0] = t4.x; xv[r][1] = t4.y; xv[r][2] = t4.z; xv[r][3] = t4.w;
    }
#pragma unroll
    for (int kk = 0; kk < 4; ++kk) {
      int k = kc * 4 + kk;
      float4 wa = *(const float4*)&Wl[k * 128 + ch];
      float4 wb = *(const float4*)&Wl[k * 128 + ch + 4];
      float wv[8] = {wa.x, wa.y, wa.z, wa.w, wb.x, wb.y, wb.z, wb.w};
#pragma unroll
      for (int r = 0; r < 4; ++r)
#pragma unroll
        for (int c = 0; c < 8; ++c) acc[r][c] = fmaf(xv[r][kk], wv[c], acc[r][c]);
    }
  }

  float bv[8];
#pragma unroll
  for (int c = 0; c < 8; ++c) bv[c] = bias[ch + c];
  float s[8], q2[8];
#pragma unroll
  for (int c = 0; c < 8; ++c) { s[c] = 0.f; q2[c] = 0.f; }
#pragma unroll
  for (int r = 0; r < 4; ++r) {
    float hv[8];
#pragma unroll
    for (int c = 0; c < 8; ++c) hv[c] = acc[r][c] + bv[c];
    *(float4*)&h[(size_t)(row0 + r) * 128 + ch] = make_float4(hv[0], hv[1], hv[2], hv[3]);
    *(float4*)&h[(size_t)(row0 + r) * 128 + ch + 4] = make_float4(hv[4], hv[5], hv[6], hv[7]);
#pragma unroll
    for (int c = 0; c < 8; ++c) { s[c] += hv[c]; q2[c] = fmaf(hv[c], hv[c], q2[c]); }
  }
#pragma unroll
  for (int off = 16; off <= 32; off <<= 1) {
#pragma unroll
    for (int c = 0; c < 8; ++c) {
      s[c] += __shfl_xor(s[c], off);
      q2[c] += __shfl_xor(q2[c], off);
    }
  }
  int wv_ = t >> 6;
  if ((t & 63) < 16) {
#pragma unroll
    for (int c = 0; c < 8; ++c) { pl[wv_][0][ch + c] = s[c]; pl[wv_][1][ch + c] = q2[c]; }
  }
  __syncthreads();
  if (t < 128) {
    float S = 0.f, Q = 0.f;
#pragma unroll
    for (int w = 0; w < 4; ++w) { S += pl[w][0][t]; Q += pl[w][1][t]; }
    part[(size_t)blockIdx.x * 256 + t] = S;
    part[(size_t)blockIdx.x * 256 + 128 + t] = Q;
  }
}

// ---------------- K2: finalize BN -> scale/shift ----------------
__global__ void k_bn(const float* __restrict__ part, const float* __restrict__ gamma,
                     const float* __restrict__ beta, float* __restrict__ ss) {
  int t = threadIdx.x;  // 128
  float S = 0.f, Q = 0.f;
  for (int b = 0; b < 512; ++b) {
    S += part[(size_t)b * 256 + t];
    Q += part[(size_t)b * 256 + 128 + t];
  }
  float mean = S * (1.0f / 32768.0f);
  float var = Q * (1.0f / 32768.0f) - mean * mean;
  var = fmaxf(var, 0.0f);
  float inv = 1.0f / sqrtf(var + 1e-5f);
  float sc = gamma[t] * inv;
  ss[t] = sc;
  ss[128 + t] = beta[t] - mean * sc;
}

// ---------------- K3: FPS — ONE WAVE, barrier-free ----------------
__global__ __launch_bounds__(64) void k_fps4(const float4* __restrict__ pk,
                                             const int* __restrict__ cstart,
                                             const float* __restrict__ p1,
                                             float* __restrict__ p2) {
  extern __shared__ float lds[];
  float* md = lds;                                  // [32768]
  unsigned* segva = (unsigned*)(lds + 32768);       // [512][2] = {val(f32 bits), packed}
  int* cst = (int*)(lds + 32768 + 1024);            // [513]
  int lane = threadIdx.x;

  for (int i = lane; i < TD_N; i += 64) md[i] = 1e10f;
  for (int i = lane; i < 513; i += 64) cst[i] = cstart[i];

  // bboxes of my 8 cells (registers, statically indexed only)
  float bx0[8], bx1[8], by0[8], by1[8], bz0[8], bz1[8];
#pragma unroll
  for (int c = 0; c < 8; ++c) {
    int d = (lane << 3) + c;
    int st = cstart[d], en = cstart[d + 1];
    float x0 = 1e30f, x1 = -1e30f, y0 = 1e30f, y1 = -1e30f, z0 = 1e30f, z1 = -1e30f;
    for (int p = st; p < en; ++p) {
      float4 v = pk[p];
      x0 = fminf(x0, v.x); x1 = fmaxf(x1, v.x);
      y0 = fminf(y0, v.y); y1 = fmaxf(y1, v.y);
      z0 = fminf(z0, v.z); z1 = fmaxf(z1, v.z);
    }
    bx0[c] = x0; bx1[c] = x1; by0[c] = y0; by1[c] = y1; bz0[c] = z0; bz1[c] = z1;
    segva[d * 2 + 0] = __float_as_uint((st < en) ? 1e10f : -1.0f);
    segva[d * 2 + 1] = 0xFFFFFFFFu;
  }
  float qx = p1[0], qy = p1[1], qz = p1[2];
  if (lane == 0) { p2[0] = qx; p2[1] = qy; p2[2] = qz; }
  __builtin_amdgcn_wave_barrier();  // compiler fence (no HW cost; 1 wave is lockstep)

  for (int it = 1; it < TD_M; ++it) {
    // fused prune + fold of clean cells into per-lane candidate
    float cv = -2.0f; unsigned cp = 0xFFFFFFFFu;
    unsigned lmask = 0;
#pragma unroll
    for (int c = 0; c < 8; ++c) {
      int d = (lane << 3) + c;
      float sv = __uint_as_float(segva[d * 2 + 0]);
      unsigned sp = segva[d * 2 + 1];
      float dxm = fmaxf(0.f, fmaxf(__fsub_rn(bx0[c], qx), __fsub_rn(qx, bx1[c])));
      float dym = fmaxf(0.f, fmaxf(__fsub_rn(by0[c], qy), __fsub_rn(qy, by1[c])));
      float dzm = fmaxf(0.f, fmaxf(__fsub_rn(bz0[c], qz), __fsub_rn(qz, bz1[c])));
      float lb2 = dxm * dxm + dym * dym + dzm * dzm;
      // safe-skip: lb2*(1-1e-5) >= segmax => no md in cell can change (margin >> 5e-7)
      if (!(lb2 * 0.99999f >= sv)) {
        lmask |= (1u << c);
      } else if (sv > cv || (sv == cv && sp < cp)) {
        cv = sv; cp = sp;
      }
    }
    unsigned long long wmask = __ballot(lmask != 0);
    while (wmask) {
      int L = (int)__builtin_ctzll(wmask); wmask &= wmask - 1;
      unsigned cm = (unsigned)__shfl((int)lmask, L);
      while (cm) {
        int c = (int)__builtin_ctz(cm); cm &= cm - 1;
        int d = (L << 3) + c;
        int st = cst[d], en = cst[d + 1];
        float bv = -2.0f; unsigned bp = 0xFFFFFFFFu;
        for (int p0 = st; p0 < en; p0 += 64) {
          int p = p0 + lane;
          if (p < en) {
            float4 v = pk[p];
            float dx = __fsub_rn(v.x, qx);
            float dy = __fsub_rn(v.y, qy);
            float dz = __fsub_rn(v.z, qz);
            float dd = fmaf(dz, dz, fmaf(dy, dy, __fmul_rn(dx, dx)));  // frozen chain
            float nm = fminf(md[p], dd);
            md[p] = nm;
            unsigned pkd = (((unsigned)__float_as_int(v.w)) << 16) | (unsigned)p;
            if (nm > bv || (nm == bv && pkd < bp)) { bv = nm; bp = pkd; }
          }
        }
#pragma unroll
        for (int off = 32; off; off >>= 1) {  // butterfly: all lanes get cell winner
          float ov = __shfl_xor(bv, off);
          unsigned op = (unsigned)__shfl_xor((int)bp, off);
          if (ov > bv || (ov == bv && op < bp)) { bv = ov; bp = op; }
        }
        if (lane == 0) { segva[d * 2 + 0] = __float_as_uint(bv); segva[d * 2 + 1] = bp; }
        if (bv > cv || (bv == cv && bp < cp)) { cv = bv; cp = bp; }
      }
    }
    // final butterfly over per-lane candidates -> global winner on all lanes
#pragma unroll
    for (int off = 32; off; off >>= 1) {
      float ov = __shfl_xor(cv, off);
      unsigned op = (unsigned)__shfl_xor((int)cp, off);
      if (ov > cv || (ov == cv && op < cp)) { cv = ov; cp = op; }
    }
    int spos = (int)(cp & 0xFFFFu);
    float4 wv = pk[spos];
    qx = wv.x; qy = wv.y; qz = wv.z;
    if (lane == 0) {
      p2[(size_t)it * 3 + 0] = qx;
      p2[(size_t)it * 3 + 1] = qy;
      p2[(size_t)it * 3 + 2] = qz;
    }
    __builtin_amdgcn_wave_barrier();
  }
}

// ---------------- K4: 16-NN — expanded f32, all-FMA chains (frozen from R5) ----------------
__device__ __forceinline__ unsigned long long shfl_xor_u64(unsigned long long v, int m) {
  unsigned lo = __shfl_xor((unsigned)v, m);
  unsigned hi = __shfl_xor((unsigned)(v >> 32), m);
  return ((unsigned long long)hi << 32) | lo;
}

__global__ __launch_bounds__(256) void k_knn(const float* __restrict__ px,
                                             const float* __restrict__ py,
                                             const float* __restrict__ pz,
                                             const float* __restrict__ pp,
                                             const float* __restrict__ p2,
                                             int* __restrict__ nb) {
  __shared__ unsigned long long mq[4][16][64];
  int wid = threadIdx.x >> 6, lane = threadIdx.x & 63;
  int q = blockIdx.x * 4 + wid;
  float qx = p2[(size_t)q * 3 + 0], qy = p2[(size_t)q * 3 + 1], qz = p2[(size_t)q * 3 + 2];
  float qq = sq3_fma(qx, qy, qz);

  unsigned long long sl[16];
#pragma unroll
  for (int s = 0; s < 16; ++s) sl[s] = ~0ULL;

#pragma unroll 2
  for (int c = 0; c < 512; ++c) {
    int i = c * 64 + lane;
    float X = px[i], Y = py[i], Z = pz[i], P = pp[i];
    float dot = fmaf(qz, Z, fmaf(qy, Y, __fmul_rn(qx, X)));       // fma-ascending
    float d2 = __fadd_rn(__fsub_rn(qq, __fadd_rn(dot, dot)), P);  // (qq - 2*dot) + pp
    unsigned u = __float_as_uint(d2);
    u ^= ((unsigned)(((int)u) >> 31)) | 0x80000000u;
    unsigned long long key = ((unsigned long long)u << 32) | (unsigned)i;
#pragma unroll
    for (int s = 0; s < 16; ++s) {
      unsigned long long lo = key < sl[s] ? key : sl[s];
      unsigned long long hi = key < sl[s] ? sl[s] : key;
      sl[s] = lo;
      key = hi;
    }
  }
#pragma unroll
  for (int s = 0; s < 16; ++s) mq[wid][s][lane] = sl[s];
  int head = 0;
  for (int r = 0; r < 16; ++r) {
    int hh = head < 16 ? head : 15;
    unsigned long long kk = mq[wid][hh][lane];
    if (head >= 16) kk = ~0ULL;
    unsigned long long v = kk;
#pragma unroll
    for (int off = 32; off; off >>= 1) {
      unsigned long long o = shfl_xor_u64(v, off);
      if (o < v) v = o;
    }
    if (kk == v) head++;
    if (lane == 0) nb[(size_t)q * 16 + r] = (int)(v & 0xffffffffULL);
  }
}

// ---------------- K5: gather + affine + relu + maxpool ----------------
__global__ __launch_bounds__(256) void k_gather(const float* __restrict__ h,
                                                const float* __restrict__ ss,
                                                const int* __restrict__ nb,
                                                float* __restrict__ y) {
  int t = threadIdx.x;
  int q = blockIdx.x * 2 + (t >> 7);
  int ch = t & 127;
  float sc = ss[ch], sh = ss[128 + ch];
  float m = -3.4e38f;
#pragma unroll
  for (int k = 0; k < 16; ++k) {
    int n = nb[(size_t)q * 16 + k];
    float v = h[(size_t)n * 128 + ch];
    m = fmaxf(m, fmaf(v, sc, sh));
  }
  y[(size_t)q * 128 + ch] = fmaxf(m, 0.0f);
}

extern "C" void kernel_launch(void* const* d_in, const int* in_sizes, int n_in,
                              void* d_out, int out_size, void* d_ws, size_t ws_size,
                              hipStream_t stream) {
  (void)in_sizes; (void)n_in; (void)out_size; (void)ws_size;
  const float* x = (const float*)d_in[0];
  const float* p1 = (const float*)d_in[1];
  const float* W = (const float*)d_in[2];
  const float* bias = (const float*)d_in[3];
  const float* gamma = (const float*)d_in[4];
  const float* beta = (const float*)d_in[5];

  float* out = (float*)d_out;
  float* y = out;                    // (8192,128)
  float* p2 = out + 1048576;         // (8192,3)

  // ws layout — identical footprint to R6/R8-proven:
  float* w = (float*)d_ws;
  float* h = w;                      // 4194304
  float* part = w + 4194304;         // 131072
  float* ss = w + 4325376;           // 256
  float* px = w + 4325632;           // 32768
  float* py = w + 4358400;
  float* pz = w + 4391168;
  float* pp = w + 4423936;
  int* nb = (int*)(w + 4456704);     // 8192*16 ints -> end 4489472 floats

  // FPS scratch in d_out's y-region (overwritten by k_gather at the very end):
  float4* pk = (float4*)y;           // 32768 float4 = 131072 floats
  int* cstart = (int*)(y + 131072);  // 513
  int* cursor = (int*)(y + 131648);  // 512   (end 132160 << 1048576)

  const int fps_lds = (32768 + 1024 + 514) * 4;  // md + segva + cst = 137224 B
  hipFuncSetAttribute((const void*)k_fps4, hipFuncAttributeMaxDynamicSharedMemorySize, fps_lds);

  k_soa<<<128, 256, 0, stream>>>(p1, px, py, pz, pp);
  k_cells<<<1, 1024, 0, stream>>>(px, py, pz, cstart, cursor);
  k_scatter<<<128, 256, 0, stream>>>(px, py, pz, cursor, pk);
  k_mlp<<<512, 256, 0, stream>>>(x, W, bias, h, part);
  k_bn<<<1, 128, 0, stream>>>(part, gamma, beta, ss);
  k_fps4<<<1, 64, fps_lds, stream>>>(pk, cstart, p1, p2);
  k_knn<<<2048, 256, 0, stream>>>(px, py, pz, pp, p2, nb);
  k_gather<<<4096, 256, 0, stream>>>(h, ss, nb, y);
}

// Round 10
// 51902.490 us; speedup vs baseline: 1.1041x; 1.1041x over previous
//
#include <hip/hip_runtime.h>
#include <cstdint>
#include <cstddef>

// TransitionDown: FPS(8192 of 32768) + 16-NN + (Linear 64->128, BN, ReLU) + gather/maxpool
// R10: FPS = 4 waves / 256 thr, ONE barrier per iteration, merged butterfly chains,
// SoA segval/segpkd (conflict-light), double-buffered wave candidates, winner via one
// L2 fetch. FROZEN numerics (R5-PASS, 4x verified): d = fmaf(dz,dz,fmaf(dy,dy,dx*dx))
// with __fsub_rn subs; fminf(old,d); kNN dot fma-asc + qq/pp fma chains; all ties ->
// lowest original index (packed key (oi<<16)|spos).

#define TD_N 32768
#define TD_M 8192

__device__ __forceinline__ float sq3_fma(float a, float b, float c) {
  return fmaf(c, c, fmaf(b, b, __fmul_rn(a, a)));
}

__device__ __forceinline__ int cell_of(float x, float y, float z) {
  int ix = min(7, (int)(x * 8.0f));
  int iy = min(7, (int)(y * 8.0f));
  int iz = min(7, (int)(z * 8.0f));
  return (iz << 6) | (iy << 3) | ix;
}

// ---------------- K0: AoS -> SoA + |p|^2 (fma chain) ----------------
__global__ void k_soa(const float* __restrict__ p1, float* __restrict__ px,
                      float* __restrict__ py, float* __restrict__ pz,
                      float* __restrict__ pp) {
  int i = blockIdx.x * 256 + threadIdx.x;
  float a = p1[i * 3 + 0], b = p1[i * 3 + 1], c = p1[i * 3 + 2];
  px[i] = a; py[i] = b; pz[i] = c;
  pp[i] = sq3_fma(a, b, c);
}

// ---------------- K0b: histogram + prefix -> cell_start, cursor ----------------
__global__ __launch_bounds__(1024) void k_cells(const float* __restrict__ px,
                                                const float* __restrict__ py,
                                                const float* __restrict__ pz,
                                                int* __restrict__ cstart,
                                                int* __restrict__ cursor) {
  __shared__ int hist[512];
  __shared__ int wsum[16];
  int t = threadIdx.x;
  if (t < 512) hist[t] = 0;
  __syncthreads();
  for (int i = t; i < TD_N; i += 1024)
    atomicAdd(&hist[cell_of(px[i], py[i], pz[i])], 1);
  __syncthreads();
  int v = (t < 512) ? hist[t] : 0;
  int lane = t & 63, w = t >> 6;
  int s = v;
#pragma unroll
  for (int off = 1; off < 64; off <<= 1) {
    int o = __shfl_up(s, off);
    if (lane >= off) s += o;
  }
  if (lane == 63) wsum[w] = s;
  __syncthreads();
  if (t == 0) { int a = 0; for (int i = 0; i < 16; ++i) { int x = wsum[i]; wsum[i] = a; a += x; } }
  __syncthreads();
  int ex = s - v + wsum[w];
  if (t < 512) { cstart[t] = ex; cursor[t] = ex; }
  if (t == 0) cstart[512] = TD_N;
}

// ---------------- K0c: scatter into cell-sorted packed float4 ----------------
// Atomic order nondeterministic, but FPS outputs are order-invariant (elementwise
// min_d updates + unique-original-index tie-breaks).
__global__ __launch_bounds__(256) void k_scatter(const float* __restrict__ px,
                                                 const float* __restrict__ py,
                                                 const float* __restrict__ pz,
                                                 int* __restrict__ cursor,
                                                 float4* __restrict__ pk) {
  int i = blockIdx.x * 256 + threadIdx.x;
  float X = px[i], Y = py[i], Z = pz[i];
  int c = cell_of(X, Y, Z);
  int pos = atomicAdd(&cursor[c], 1);
  pk[pos] = make_float4(X, Y, Z, __int_as_float(i));
}

// ---------------- K1: h = x@W + b, + per-block BN partial sums ----------------
__global__ __launch_bounds__(256) void k_mlp(const float* __restrict__ x,
                                             const float* __restrict__ W,
                                             const float* __restrict__ bias,
                                             float* __restrict__ h,
                                             float* __restrict__ part) {
  __shared__ float Wl[64 * 128];
  __shared__ float pl[4][2][128];
  int t = threadIdx.x;
#pragma unroll
  for (int i = 0; i < 8; ++i) {
    int f4 = t + i * 256;
    ((float4*)Wl)[f4] = ((const float4*)W)[f4];
  }
  __syncthreads();

  int rg = t >> 4;
  int ch = (t & 15) * 8;
  int row0 = blockIdx.x * 64 + rg * 4;

  float acc[4][8];
#pragma unroll
  for (int r = 0; r < 4; ++r)
#pragma unroll
    for (int c = 0; c < 8; ++c) acc[r][c] = 0.f;

  const float* xrow = x + (size_t)row0 * 64;
#pragma unroll 4
  for (int kc = 0; kc < 16; ++kc) {
    float xv[4][4];
#pragma unroll
    for (int r = 0; r < 4; ++r) {
      float4 t4 = *(const float4*)(xrow + r * 64 + kc * 4);
      xv[r][0] = t4.x; xv[r][1] = t4.y; xv[r][2] = t4.z; xv[r][3] = t4.w;
    }
#pragma unroll
    for (int kk = 0; kk < 4; ++kk) {
      int k = kc * 4 + kk;
      float4 wa = *(const float4*)&Wl[k * 128 + ch];
      float4 wb = *(const float4*)&Wl[k * 128 + ch + 4];
      float wv[8] = {wa.x, wa.y, wa.z, wa.w, wb.x, wb.y, wb.z, wb.w};
#pragma unroll
      for (int r = 0; r < 4; ++r)
#pragma unroll
        for (int c = 0; c < 8; ++c) acc[r][c] = fmaf(xv[r][kk], wv[c], acc[r][c]);
    }
  }

  float bv[8];
#pragma unroll
  for (int c = 0; c < 8; ++c) bv[c] = bias[ch + c];
  float s[8], q2[8];
#pragma unroll
  for (int c = 0; c < 8; ++c) { s[c] = 0.f; q2[c] = 0.f; }
#pragma unroll
  for (int r = 0; r < 4; ++r) {
    float hv[8];
#pragma unroll
    for (int c = 0; c < 8; ++c) hv[c] = acc[r][c] + bv[c];
    *(float4*)&h[(size_t)(row0 + r) * 128 + ch] = make_float4(hv[0], hv[1], hv[2], hv[3]);
    *(float4*)&h[(size_t)(row0 + r) * 128 + ch + 4] = make_float4(hv[4], hv[5], hv[6], hv[7]);
#pragma unroll
    for (int c = 0; c < 8; ++c) { s[c] += hv[c]; q2[c] = fmaf(hv[c], hv[c], q2[c]); }
  }
#pragma unroll
  for (int off = 16; off <= 32; off <<= 1) {
#pragma unroll
    for (int c = 0; c < 8; ++c) {
      s[c] += __shfl_xor(s[c], off);
      q2[c] += __shfl_xor(q2[c], off);
    }
  }
  int wv_ = t >> 6;
  if ((t & 63) < 16) {
#pragma unroll
    for (int c = 0; c < 8; ++c) { pl[wv_][0][ch + c] = s[c]; pl[wv_][1][ch + c] = q2[c]; }
  }
  __syncthreads();
  if (t < 128) {
    float S = 0.f, Q = 0.f;
#pragma unroll
    for (int w = 0; w < 4; ++w) { S += pl[w][0][t]; Q += pl[w][1][t]; }
    part[(size_t)blockIdx.x * 256 + t] = S;
    part[(size_t)blockIdx.x * 256 + 128 + t] = Q;
  }
}

// ---------------- K2: finalize BN -> scale/shift ----------------
__global__ void k_bn(const float* __restrict__ part, const float* __restrict__ gamma,
                     const float* __restrict__ beta, float* __restrict__ ss) {
  int t = threadIdx.x;  // 128
  float S = 0.f, Q = 0.f;
  for (int b = 0; b < 512; ++b) {
    S += part[(size_t)b * 256 + t];
    Q += part[(size_t)b * 256 + 128 + t];
  }
  float mean = S * (1.0f / 32768.0f);
  float var = Q * (1.0f / 32768.0f) - mean * mean;
  var = fmaxf(var, 0.0f);
  float inv = 1.0f / sqrtf(var + 1e-5f);
  float sc = gamma[t] * inv;
  ss[t] = sc;
  ss[128 + t] = beta[t] - mean * sc;
}

// ---------------- K3: FPS — 4 waves, 1 barrier/iter ----------------
#define FOLD(V, P, NV, NP) \
  if ((NV) > (V) || ((NV) == (V) && (NP) < (P))) { (V) = (NV); (P) = (NP); }

#define SCAN_CELL(DD, BV, BP)                                              \
  {                                                                        \
    int st_ = cst[DD], en_ = cst[(DD) + 1];                                \
    for (int p0_ = st_; p0_ < en_; p0_ += 64) {                            \
      int p_ = p0_ + lane;                                                 \
      if (p_ < en_) {                                                      \
        float4 v_ = pk[p_];                                                \
        float om_ = md[p_];                                                \
        float dx_ = __fsub_rn(v_.x, qx);                                   \
        float dy_ = __fsub_rn(v_.y, qy);                                   \
        float dz_ = __fsub_rn(v_.z, qz);                                   \
        float d2_ = fmaf(dz_, dz_, fmaf(dy_, dy_, __fmul_rn(dx_, dx_)));   \
        float nm_ = fminf(om_, d2_);                                       \
        md[p_] = nm_;                                                      \
        unsigned pk_ = (((unsigned)__float_as_int(v_.w)) << 16) | (unsigned)p_; \
        FOLD(BV, BP, nm_, pk_)                                             \
      }                                                                    \
    }                                                                      \
  }

__global__ __launch_bounds__(256) void k_fps5(const float4* __restrict__ pk,
                                              const int* __restrict__ cstart,
                                              const float* __restrict__ p1,
                                              float* __restrict__ p2) {
  extern __shared__ float lds[];
  float* md = lds;                            // [32768]
  float* segval = lds + 32768;                // [512]
  unsigned* segpkd = (unsigned*)(lds + 33280);// [512]
  int* cst = (int*)(lds + 33792);             // [516 pad]
  unsigned* wc = (unsigned*)(lds + 34308);    // [2][8]: 4 waves x (valbits, pkd)

  int t = threadIdx.x;
  int lane = t & 63, w = t >> 6;

  for (int i = t; i < TD_N; i += 256) md[i] = 1e10f;
  for (int i = t; i < 513; i += 256) {
    int v = cstart[i];
    cst[i] = min(max(v, 0), TD_N);
  }
  __syncthreads();

  // per-lane: own cells d0, d0+1; bboxes in registers
  int d0 = (w << 7) + (lane << 1);
  float bx0[2], bx1[2], by0[2], by1[2], bz0[2], bz1[2];
#pragma unroll
  for (int c = 0; c < 2; ++c) {
    int d = d0 + c;
    int st = cst[d], en = cst[d + 1];
    float x0 = 1e30f, x1 = -1e30f, y0 = 1e30f, y1 = -1e30f, z0 = 1e30f, z1 = -1e30f;
    for (int p = st; p < en; ++p) {
      float4 v = pk[p];
      x0 = fminf(x0, v.x); x1 = fmaxf(x1, v.x);
      y0 = fminf(y0, v.y); y1 = fmaxf(y1, v.y);
      z0 = fminf(z0, v.z); z1 = fmaxf(z1, v.z);
    }
    bx0[c] = x0; bx1[c] = x1; by0[c] = y0; by1[c] = y1; bz0[c] = z0; bz1[c] = z1;
    segval[d] = (st < en) ? 1e10f : -1.0f;
    segpkd[d] = 0xFFFFFFFFu;
  }
  float qx = p1[0], qy = p1[1], qz = p1[2];
  if (t == 0) { p2[0] = qx; p2[1] = qy; p2[2] = qz; }
  __syncthreads();

  for (int it = 1; it < TD_M; ++it) {
    // ---- prune my 2 cells; fold clean into per-lane candidate (cv,cp) ----
    float cv = -2.0f; unsigned cp = 0xFFFFFFFFu;
    unsigned rem = 0;
#pragma unroll
    for (int c = 0; c < 2; ++c) {
      int d = d0 + c;
      float sv = segval[d];
      unsigned sp = segpkd[d];
      float dxm = fmaxf(0.f, fmaxf(__fsub_rn(bx0[c], qx), __fsub_rn(qx, bx1[c])));
      float dym = fmaxf(0.f, fmaxf(__fsub_rn(by0[c], qy), __fsub_rn(qy, by1[c])));
      float dzm = fmaxf(0.f, fmaxf(__fsub_rn(bz0[c], qz), __fsub_rn(qz, bz1[c])));
      float lb2 = dxm * dxm + dym * dym + dzm * dzm;
      // safe-skip: lb2*(1-1e-5) >= segmax => no md in cell can change (chain err ~1e-6)
      if (!(lb2 * 0.99999f >= sv)) rem |= (1u << c);
      else FOLD(cv, cp, sv, sp)
    }
    // ---- batches of up to 4 dirty cells; merged butterfly chains ----
    bool didbf = false;
    for (;;) {
      unsigned long long act = __ballot(rem != 0);
      if (!act) break;
      int nb = 0;
      int dA = 0, dB = 0, dC = 0, dD = 0;
      while (nb < 4 && act) {
        int L = (int)__builtin_ctzll(act);
        unsigned rm = (unsigned)__shfl((int)rem, L);
        int c = (int)__builtin_ctz(rm);
        int dnew = (w << 7) + (L << 1) + c;
        if (nb == 0) dA = dnew; else if (nb == 1) dB = dnew;
        else if (nb == 2) dC = dnew; else dD = dnew;
        ++nb;
        rm &= rm - 1;
        if (lane == L) rem = rm;
        if (rm == 0) act &= ~(1ULL << L);
      }
      float bvA = -2.f, bvB = -2.f, bvC = -2.f, bvD = -2.f;
      unsigned bpA = 0xFFFFFFFFu, bpB = 0xFFFFFFFFu, bpC = 0xFFFFFFFFu, bpD = 0xFFFFFFFFu;
      SCAN_CELL(dA, bvA, bpA)
      if (nb > 1) SCAN_CELL(dB, bvB, bpB)
      if (nb > 2) SCAN_CELL(dC, bvC, bpC)
      if (nb > 3) SCAN_CELL(dD, bvD, bpD)
      // fold cell partials into comb BEFORE butterfly (associativity of max)
      FOLD(cv, cp, bvA, bpA)
      FOLD(cv, cp, bvB, bpB)
      FOLD(cv, cp, bvC, bpC)
      FOLD(cv, cp, bvD, bpD)
      if (nb == 1) {
#pragma unroll
        for (int off = 32; off; off >>= 1) {
          float oA = __shfl_xor(bvA, off); unsigned pA = (unsigned)__shfl_xor((int)bpA, off);
          float oC = __shfl_xor(cv, off);  unsigned pC = (unsigned)__shfl_xor((int)cp, off);
          FOLD(bvA, bpA, oA, pA)
          FOLD(cv, cp, oC, pC)
        }
      } else {
#pragma unroll
        for (int off = 32; off; off >>= 1) {
          float oA = __shfl_xor(bvA, off); unsigned pA = (unsigned)__shfl_xor((int)bpA, off);
          float oB = __shfl_xor(bvB, off); unsigned pB = (unsigned)__shfl_xor((int)bpB, off);
          float oC2 = __shfl_xor(bvC, off); unsigned pC2 = (unsigned)__shfl_xor((int)bpC, off);
          float oD = __shfl_xor(bvD, off); unsigned pD = (unsigned)__shfl_xor((int)bpD, off);
          float oc = __shfl_xor(cv, off);  unsigned pc = (unsigned)__shfl_xor((int)cp, off);
          FOLD(bvA, bpA, oA, pA)
          FOLD(bvB, bpB, oB, pB)
          FOLD(bvC, bpC, oC2, pC2)
          FOLD(bvD, bpD, oD, pD)
          FOLD(cv, cp, oc, pc)
        }
      }
      didbf = true;
      if (lane == 0) {
        segval[dA] = bvA; segpkd[dA] = bpA;
        if (nb > 1) { segval[dB] = bvB; segpkd[dB] = bpB; }
        if (nb > 2) { segval[dC] = bvC; segpkd[dC] = bpC; }
        if (nb > 3) { segval[dD] = bvD; segpkd[dD] = bpD; }
      }
    }
    if (!didbf) {
#pragma unroll
      for (int off = 32; off; off >>= 1) {
        float oc = __shfl_xor(cv, off);
        unsigned pc = (unsigned)__shfl_xor((int)cp, off);
        FOLD(cv, cp, oc, pc)
      }
    }
    if (lane == 0) {
      wc[(it & 1) * 8 + w * 2 + 0] = __float_as_uint(cv);
      wc[(it & 1) * 8 + w * 2 + 1] = cp;
    }
    __syncthreads();
    // ---- fold 4 wave candidates (broadcast LDS reads, no shuffles) ----
    {
      const uint4* wq = (const uint4*)&wc[(it & 1) * 8];
      uint4 a = wq[0], b = wq[1];
      float gv = __uint_as_float(a.x); unsigned gp = a.y;
      FOLD(gv, gp, __uint_as_float(a.z), a.w)
      FOLD(gv, gp, __uint_as_float(b.x), b.y)
      FOLD(gv, gp, __uint_as_float(b.z), b.w)
      int spos = (int)(gp & (unsigned)(TD_N - 1));
      float4 wv = pk[spos];
      qx = wv.x; qy = wv.y; qz = wv.z;
      if (t == 0) {
        p2[(size_t)it * 3 + 0] = qx;
        p2[(size_t)it * 3 + 1] = qy;
        p2[(size_t)it * 3 + 2] = qz;
      }
    }
    // no second barrier needed: segval/segpkd are wave-private (owner wave r/w);
    // wc is double-buffered by iteration parity.
  }
}

// ---------------- K4: 16-NN — expanded f32, all-FMA chains (frozen from R5) ----------------
__device__ __forceinline__ unsigned long long shfl_xor_u64(unsigned long long v, int m) {
  unsigned lo = __shfl_xor((unsigned)v, m);
  unsigned hi = __shfl_xor((unsigned)(v >> 32), m);
  return ((unsigned long long)hi << 32) | lo;
}

__global__ __launch_bounds__(256) void k_knn(const float* __restrict__ px,
                                             const float* __restrict__ py,
                                             const float* __restrict__ pz,
                                             const float* __restrict__ pp,
                                             const float* __restrict__ p2,
                                             int* __restrict__ nb) {
  __shared__ unsigned long long mq[4][16][64];
  int wid = threadIdx.x >> 6, lane = threadIdx.x & 63;
  int q = blockIdx.x * 4 + wid;
  float qx = p2[(size_t)q * 3 + 0], qy = p2[(size_t)q * 3 + 1], qz = p2[(size_t)q * 3 + 2];
  float qq = sq3_fma(qx, qy, qz);

  unsigned long long sl[16];
#pragma unroll
  for (int s = 0; s < 16; ++s) sl[s] = ~0ULL;

#pragma unroll 2
  for (int c = 0; c < 512; ++c) {
    int i = c * 64 + lane;
    float X = px[i], Y = py[i], Z = pz[i], P = pp[i];
    float dot = fmaf(qz, Z, fmaf(qy, Y, __fmul_rn(qx, X)));       // fma-ascending
    float d2 = __fadd_rn(__fsub_rn(qq, __fadd_rn(dot, dot)), P);  // (qq - 2*dot) + pp
    unsigned u = __float_as_uint(d2);
    u ^= ((unsigned)(((int)u) >> 31)) | 0x80000000u;
    unsigned long long key = ((unsigned long long)u << 32) | (unsigned)i;
#pragma unroll
    for (int s = 0; s < 16; ++s) {
      unsigned long long lo = key < sl[s] ? key : sl[s];
      unsigned long long hi = key < sl[s] ? sl[s] : key;
      sl[s] = lo;
      key = hi;
    }
  }
#pragma unroll
  for (int s = 0; s < 16; ++s) mq[wid][s][lane] = sl[s];
  int head = 0;
  for (int r = 0; r < 16; ++r) {
    int hh = head < 16 ? head : 15;
    unsigned long long kk = mq[wid][hh][lane];
    if (head >= 16) kk = ~0ULL;
    unsigned long long v = kk;
#pragma unroll
    for (int off = 32; off; off >>= 1) {
      unsigned long long o = shfl_xor_u64(v, off);
      if (o < v) v = o;
    }
    if (kk == v) head++;
    if (lane == 0) nb[(size_t)q * 16 + r] = (int)(v & 0xffffffffULL);
  }
}

// ---------------- K5: gather + affine + relu + maxpool ----------------
__global__ __launch_bounds__(256) void k_gather(const float* __restrict__ h,
                                                const float* __restrict__ ss,
                                                const int* __restrict__ nb,
                                                float* __restrict__ y) {
  int t = threadIdx.x;
  int q = blockIdx.x * 2 + (t >> 7);
  int ch = t & 127;
  float sc = ss[ch], sh = ss[128 + ch];
  float m = -3.4e38f;
#pragma unroll
  for (int k = 0; k < 16; ++k) {
    int n = nb[(size_t)q * 16 + k];
    float v = h[(size_t)n * 128 + ch];
    m = fmaxf(m, fmaf(v, sc, sh));
  }
  y[(size_t)q * 128 + ch] = fmaxf(m, 0.0f);
}

extern "C" void kernel_launch(void* const* d_in, const int* in_sizes, int n_in,
                              void* d_out, int out_size, void* d_ws, size_t ws_size,
                              hipStream_t stream) {
  (void)in_sizes; (void)n_in; (void)out_size; (void)ws_size;
  const float* x = (const float*)d_in[0];
  const float* p1 = (const float*)d_in[1];
  const float* W = (const float*)d_in[2];
  const float* bias = (const float*)d_in[3];
  const float* gamma = (const float*)d_in[4];
  const float* beta = (const float*)d_in[5];

  float* out = (float*)d_out;
  float* y = out;                    // (8192,128)
  float* p2 = out + 1048576;         // (8192,3)

  // ws layout — identical footprint to R6/R8-proven:
  float* w = (float*)d_ws;
  float* h = w;                      // 4194304
  float* part = w + 4194304;         // 131072
  float* ss = w + 4325376;           // 256
  float* px = w + 4325632;           // 32768
  float* py = w + 4358400;
  float* pz = w + 4391168;
  float* pp = w + 4423936;
  int* nb = (int*)(w + 4456704);     // 8192*16 ints -> end 4489472 floats

  // FPS scratch in d_out's y-region (overwritten by k_gather at the very end):
  float4* pk = (float4*)y;           // 32768 float4 = 131072 floats
  int* cstart = (int*)(y + 131072);  // 513
  int* cursor = (int*)(y + 131648);  // 512   (end 132160 << 1048576)

  // md 32768 + segval 512 + segpkd 512 + cst 516 + wc 16 = 34324 floats
  const int fps_lds = 34324 * 4;
  hipFuncSetAttribute((const void*)k_fps5, hipFuncAttributeMaxDynamicSharedMemorySize, fps_lds);

  k_soa<<<128, 256, 0, stream>>>(p1, px, py, pz, pp);
  k_cells<<<1, 1024, 0, stream>>>(px, py, pz, cstart, cursor);
  k_scatter<<<128, 256, 0, stream>>>(px, py, pz, cursor, pk);
  k_mlp<<<512, 256, 0, stream>>>(x, W, bias, h, part);
  k_bn<<<1, 128, 0, stream>>>(part, gamma, beta, ss);
  k_fps5<<<1, 256, fps_lds, stream>>>(pk, cstart, p1, p2);
  k_knn<<<2048, 256, 0, stream>>>(px, py, pz, pp, p2, nb);
  k_gather<<<4096, 256, 0, stream>>>(h, ss, nb, y);
}

// Round 11
// 24252.789 us; speedup vs baseline: 2.3628x; 2.1401x over previous
//
#include <hip/hip_runtime.h>
#include <cstdint>
#include <cstddef>

// TransitionDown: FPS(8192 of 32768) + 16-NN + (Linear 64->128, BN, ReLU) + gather/maxpool
// R11: FPS = 512 thr / 8 waves; lane==cell (bbox+range+segmax ALL in registers);
// DPP-based reduces (row_shr/bcast + readlane, ~100cyc vs ~720 for ds_bpermute chains);
// 1 barrier/iter (parity wc slots); p2 buffered in LDS ring, flushed every 512 iters.
// FROZEN numerics (R5-PASS, 6x verified): d = fmaf(dz,dz,fmaf(dy,dy,dx*dx)) with
// __fsub_rn subs; fminf(old,d); kNN dot fma-asc + qq/pp fma chains; ties -> lowest
// original index via unique packed key (oi<<16)|spos.

#define TD_N 32768
#define TD_M 8192

#define ROW_SHR1 0x111
#define ROW_SHR2 0x112
#define ROW_SHR4 0x114
#define ROW_SHR8 0x118
#define ROW_BCAST15 0x142
#define ROW_BCAST31 0x143

#define FOLD(V, P, NV, NP) \
  if ((NV) > (V) || ((NV) == (V) && (NP) < (P))) { (V) = (NV); (P) = (NP); }

// invalid-source lanes keep old value (bound_ctrl=false) => fold(self) = no-op
#define DPP_STEP(V, P, CTRL)                                                          \
  {                                                                                   \
    float nv_ = __int_as_float(__builtin_amdgcn_update_dpp(                           \
        __float_as_int(V), __float_as_int(V), CTRL, 0xF, 0xF, false));                \
    unsigned np_ = (unsigned)__builtin_amdgcn_update_dpp(                             \
        (int)(P), (int)(P), CTRL, 0xF, 0xF, false);                                   \
    FOLD(V, P, nv_, np_)                                                              \
  }

#define DPP_REDUCE64(V, P)                                                            \
  DPP_STEP(V, P, ROW_SHR1) DPP_STEP(V, P, ROW_SHR2) DPP_STEP(V, P, ROW_SHR4)          \
  DPP_STEP(V, P, ROW_SHR8) DPP_STEP(V, P, ROW_BCAST15) DPP_STEP(V, P, ROW_BCAST31)

__device__ __forceinline__ float sq3_fma(float a, float b, float c) {
  return fmaf(c, c, fmaf(b, b, __fmul_rn(a, a)));
}

__device__ __forceinline__ int cell_of(float x, float y, float z) {
  int ix = min(7, (int)(x * 8.0f));
  int iy = min(7, (int)(y * 8.0f));
  int iz = min(7, (int)(z * 8.0f));
  return (iz << 6) | (iy << 3) | ix;
}

// ---------------- K0: AoS -> SoA + |p|^2 (fma chain) ----------------
__global__ void k_soa(const float* __restrict__ p1, float* __restrict__ px,
                      float* __restrict__ py, float* __restrict__ pz,
                      float* __restrict__ pp) {
  int i = blockIdx.x * 256 + threadIdx.x;
  float a = p1[i * 3 + 0], b = p1[i * 3 + 1], c = p1[i * 3 + 2];
  px[i] = a; py[i] = b; pz[i] = c;
  pp[i] = sq3_fma(a, b, c);
}

// ---------------- K0b: histogram + prefix -> cell_start, cursor ----------------
__global__ __launch_bounds__(1024) void k_cells(const float* __restrict__ px,
                                                const float* __restrict__ py,
                                                const float* __restrict__ pz,
                                                int* __restrict__ cstart,
                                                int* __restrict__ cursor) {
  __shared__ int hist[512];
  __shared__ int wsum[16];
  int t = threadIdx.x;
  if (t < 512) hist[t] = 0;
  __syncthreads();
  for (int i = t; i < TD_N; i += 1024)
    atomicAdd(&hist[cell_of(px[i], py[i], pz[i])], 1);
  __syncthreads();
  int v = (t < 512) ? hist[t] : 0;
  int lane = t & 63, w = t >> 6;
  int s = v;
#pragma unroll
  for (int off = 1; off < 64; off <<= 1) {
    int o = __shfl_up(s, off);
    if (lane >= off) s += o;
  }
  if (lane == 63) wsum[w] = s;
  __syncthreads();
  if (t == 0) { int a = 0; for (int i = 0; i < 16; ++i) { int x = wsum[i]; wsum[i] = a; a += x; } }
  __syncthreads();
  int ex = s - v + wsum[w];
  if (t < 512) { cstart[t] = ex; cursor[t] = ex; }
  if (t == 0) cstart[512] = TD_N;
}

// ---------------- K0c: scatter into cell-sorted packed float4 ----------------
// Atomic order nondeterministic, but FPS outputs are order-invariant (elementwise
// min_d updates + unique-original-index tie-breaks).
__global__ __launch_bounds__(256) void k_scatter(const float* __restrict__ px,
                                                 const float* __restrict__ py,
                                                 const float* __restrict__ pz,
                                                 int* __restrict__ cursor,
                                                 float4* __restrict__ pk) {
  int i = blockIdx.x * 256 + threadIdx.x;
  float X = px[i], Y = py[i], Z = pz[i];
  int c = cell_of(X, Y, Z);
  int pos = atomicAdd(&cursor[c], 1);
  pk[pos] = make_float4(X, Y, Z, __int_as_float(i));
}

// ---------------- K1: h = x@W + b, + per-block BN partial sums ----------------
__global__ __launch_bounds__(256) void k_mlp(const float* __restrict__ x,
                                             const float* __restrict__ W,
                                             const float* __restrict__ bias,
                                             float* __restrict__ h,
                                             float* __restrict__ part) {
  __shared__ float Wl[64 * 128];
  __shared__ float pl[4][2][128];
  int t = threadIdx.x;
#pragma unroll
  for (int i = 0; i < 8; ++i) {
    int f4 = t + i * 256;
    ((float4*)Wl)[f4] = ((const float4*)W)[f4];
  }
  __syncthreads();

  int rg = t >> 4;
  int ch = (t & 15) * 8;
  int row0 = blockIdx.x * 64 + rg * 4;

  float acc[4][8];
#pragma unroll
  for (int r = 0; r < 4; ++r)
#pragma unroll
    for (int c = 0; c < 8; ++c) acc[r][c] = 0.f;

  const float* xrow = x + (size_t)row0 * 64;
#pragma unroll 4
  for (int kc = 0; kc < 16; ++kc) {
    float xv[4][4];
#pragma unroll
    for (int r = 0; r < 4; ++r) {
      float4 t4 = *(const float4*)(xrow + r * 64 + kc * 4);
      xv[r][0] = t4.x; xv[r][1] = t4.y; xv[r][2] = t4.z; xv[r][3] = t4.w;
    }
#pragma unroll
    for (int kk = 0; kk < 4; ++kk) {
      int k = kc * 4 + kk;
      float4 wa = *(const float4*)&Wl[k * 128 + ch];
      float4 wb = *(const float4*)&Wl[k * 128 + ch + 4];
      float wv[8] = {wa.x, wa.y, wa.z, wa.w, wb.x, wb.y, wb.z, wb.w};
#pragma unroll
      for (int r = 0; r < 4; ++r)
#pragma unroll
        for (int c = 0; c < 8; ++c) acc[r][c] = fmaf(xv[r][kk], wv[c], acc[r][c]);
    }
  }

  float bv[8];
#pragma unroll
  for (int c = 0; c < 8; ++c) bv[c] = bias[ch + c];
  float s[8], q2[8];
#pragma unroll
  for (int c = 0; c < 8; ++c) { s[c] = 0.f; q2[c] = 0.f; }
#pragma unroll
  for (int r = 0; r < 4; ++r) {
    float hv[8];
#pragma unroll
    for (int c = 0; c < 8; ++c) hv[c] = acc[r][c] + bv[c];
    *(float4*)&h[(size_t)(row0 + r) * 128 + ch] = make_float4(hv[0], hv[1], hv[2], hv[3]);
    *(float4*)&h[(size_t)(row0 + r) * 128 + ch + 4] = make_float4(hv[4], hv[5], hv[6], hv[7]);
#pragma unroll
    for (int c = 0; c < 8; ++c) { s[c] += hv[c]; q2[c] = fmaf(hv[c], hv[c], q2[c]); }
  }
#pragma unroll
  for (int off = 16; off <= 32; off <<= 1) {
#pragma unroll
    for (int c = 0; c < 8; ++c) {
      s[c] += __shfl_xor(s[c], off);
      q2[c] += __shfl_xor(q2[c], off);
    }
  }
  int wv_ = t >> 6;
  if ((t & 63) < 16) {
#pragma unroll
    for (int c = 0; c < 8; ++c) { pl[wv_][0][ch + c] = s[c]; pl[wv_][1][ch + c] = q2[c]; }
  }
  __syncthreads();
  if (t < 128) {
    float S = 0.f, Q = 0.f;
#pragma unroll
    for (int w = 0; w < 4; ++w) { S += pl[w][0][t]; Q += pl[w][1][t]; }
    part[(size_t)blockIdx.x * 256 + t] = S;
    part[(size_t)blockIdx.x * 256 + 128 + t] = Q;
  }
}

// ---------------- K2: finalize BN -> scale/shift ----------------
__global__ void k_bn(const float* __restrict__ part, const float* __restrict__ gamma,
                     const float* __restrict__ beta, float* __restrict__ ss) {
  int t = threadIdx.x;  // 128
  float S = 0.f, Q = 0.f;
  for (int b = 0; b < 512; ++b) {
    S += part[(size_t)b * 256 + t];
    Q += part[(size_t)b * 256 + 128 + t];
  }
  float mean = S * (1.0f / 32768.0f);
  float var = Q * (1.0f / 32768.0f) - mean * mean;
  var = fmaxf(var, 0.0f);
  float inv = 1.0f / sqrtf(var + 1e-5f);
  float sc = gamma[t] * inv;
  ss[t] = sc;
  ss[128 + t] = beta[t] - mean * sc;
}

// ---------------- K3: FPS — 512 thr, lane==cell, DPP reduces, 1 barrier/iter ----------------
__global__ __launch_bounds__(512) void k_fps6(const float4* __restrict__ pk,
                                              const int* __restrict__ cstart,
                                              const float* __restrict__ p1,
                                              float* __restrict__ p2) {
  extern __shared__ float lds[];
  float* md = lds;                                   // [32768]
  unsigned* wc = (unsigned*)(lds + 32768);           // [2][8][2] u32
  unsigned* winbuf = (unsigned*)(lds + 32768 + 32);  // [512] u32

  int t = threadIdx.x;
  int lane = t & 63, w = t >> 6;

  for (int i = t; i < TD_N; i += 512) md[i] = 1e10f;

  // my cell = w*64 + lane; bbox + range + seg-state ALL in registers
  int myc = (w << 6) | lane;
  int stR = cstart[myc], enR = cstart[myc + 1];
  stR = min(max(stR, 0), TD_N);
  enR = min(max(enR, stR), TD_N);
  float bx0 = 1e30f, bx1 = -1e30f, by0 = 1e30f, by1 = -1e30f, bz0 = 1e30f, bz1 = -1e30f;
  for (int p = stR; p < enR; ++p) {
    float4 v = pk[p];
    bx0 = fminf(bx0, v.x); bx1 = fmaxf(bx1, v.x);
    by0 = fminf(by0, v.y); by1 = fmaxf(by1, v.y);
    bz0 = fminf(bz0, v.z); bz1 = fmaxf(bz1, v.z);
  }
  float sv = (stR < enR) ? 1e10f : -1.0f;   // seg max value
  unsigned sp = 0xFFFFFFFFu;                // seg argmax packed (oi<<16)|spos
  float qx = p1[0], qy = p1[1], qz = p1[2];
  if (t == 0) { p2[0] = qx; p2[1] = qy; p2[2] = qz; }
  __syncthreads();

  for (int it = 1; it < TD_M; ++it) {
    // ---- prune my cell (registers only) ----
    float dxm = fmaxf(0.f, fmaxf(__fsub_rn(bx0, qx), __fsub_rn(qx, bx1)));
    float dym = fmaxf(0.f, fmaxf(__fsub_rn(by0, qy), __fsub_rn(qy, by1)));
    float dzm = fmaxf(0.f, fmaxf(__fsub_rn(bz0, qz), __fsub_rn(qz, bz1)));
    float lb2 = dxm * dxm + dym * dym + dzm * dzm;
    // safe-skip: lb2*(1-1e-5) >= segmax => no md in cell can change (chain err ~1e-6)
    bool dirty = !(lb2 * 0.99999f >= sv);
    float cv; unsigned cp;
    if (dirty) { cv = -2.0f; cp = 0xFFFFFFFFu; } else { cv = sv; cp = sp; }

    // ---- scan dirty cells (wave-uniform walk; DPP reduce per cell) ----
    unsigned long long mask = __ballot(dirty);
    while (mask) {
      int cl = (int)__builtin_ctzll(mask); mask &= mask - 1;
      int st = __builtin_amdgcn_readlane(stR, cl);
      int en = __builtin_amdgcn_readlane(enR, cl);
      float bv = -2.0f; unsigned bp = 0xFFFFFFFFu;
      for (int p0 = st; p0 < en; p0 += 64) {
        int p = p0 + lane;
        if (p < en) {
          float4 v = pk[p];
          float dx = __fsub_rn(v.x, qx);
          float dy = __fsub_rn(v.y, qy);
          float dz = __fsub_rn(v.z, qz);
          float d2 = fmaf(dz, dz, fmaf(dy, dy, __fmul_rn(dx, dx)));  // frozen chain
          float nm = fminf(md[p], d2);
          md[p] = nm;
          unsigned pkd = (((unsigned)__float_as_int(v.w)) << 16) | (unsigned)p;
          FOLD(bv, bp, nm, pkd)
        }
      }
      DPP_REDUCE64(bv, bp)
      float rbv = __int_as_float(__builtin_amdgcn_readlane(__float_as_int(bv), 63));
      unsigned rbp = (unsigned)__builtin_amdgcn_readlane((int)bp, 63);
      if (lane == cl) { sv = rbv; sp = rbp; }  // owner lane caches new seg state
      FOLD(cv, cp, rbv, rbp)
    }

    // ---- wave candidate -> LDS slot (parity-buffered), one barrier ----
    DPP_REDUCE64(cv, cp)
    if (lane == 63) {
      int par = (it & 1) << 4;
      wc[par + w * 2 + 0] = __float_as_uint(cv);
      wc[par + w * 2 + 1] = cp;
    }
    __syncthreads();

    // ---- all waves: fold 8 slots via DPP over lanes 0..7 ----
    unsigned gp;
    {
      int par = (it & 1) << 4;
      float v_; unsigned p_;
      if (lane < 8) {
        v_ = __uint_as_float(wc[par + lane * 2 + 0]);
        p_ = wc[par + lane * 2 + 1];
      } else { v_ = -2.0f; p_ = 0xFFFFFFFFu; }
      DPP_STEP(v_, p_, ROW_SHR1) DPP_STEP(v_, p_, ROW_SHR2) DPP_STEP(v_, p_, ROW_SHR4)
      gp = (unsigned)__builtin_amdgcn_readlane((int)p_, 7);
    }
    int spos = (int)(gp & 0xFFFFu);
    float4 wv = pk[spos];  // uniform address -> one L2 fetch per wave
    qx = wv.x; qy = wv.y; qz = wv.z;
    if (t == 0) winbuf[it & 511] = (unsigned)spos;

    // ---- flush p2 every 512 iterations (keeps global stores off the hot path) ----
    if ((it & 511) == 511) {
      __syncthreads();
      int j = it - 511 + t;
      if (j >= 1 && j <= it) {
        int sj = (int)winbuf[j & 511];
        float4 v = pk[sj];
        p2[(size_t)j * 3 + 0] = v.x;
        p2[(size_t)j * 3 + 1] = v.y;
        p2[(size_t)j * 3 + 2] = v.z;
      }
    }
  }
}

// ---------------- K4: 16-NN — expanded f32, all-FMA chains (frozen from R5) ----------------
__device__ __forceinline__ unsigned long long shfl_xor_u64(unsigned long long v, int m) {
  unsigned lo = __shfl_xor((unsigned)v, m);
  unsigned hi = __shfl_xor((unsigned)(v >> 32), m);
  return ((unsigned long long)hi << 32) | lo;
}

__global__ __launch_bounds__(256) void k_knn(const float* __restrict__ px,
                                             const float* __restrict__ py,
                                             const float* __restrict__ pz,
                                             const float* __restrict__ pp,
                                             const float* __restrict__ p2,
                                             int* __restrict__ nb) {
  __shared__ unsigned long long mq[4][16][64];
  int wid = threadIdx.x >> 6, lane = threadIdx.x & 63;
  int q = blockIdx.x * 4 + wid;
  float qx = p2[(size_t)q * 3 + 0], qy = p2[(size_t)q * 3 + 1], qz = p2[(size_t)q * 3 + 2];
  float qq = sq3_fma(qx, qy, qz);

  unsigned long long sl[16];
#pragma unroll
  for (int s = 0; s < 16; ++s) sl[s] = ~0ULL;

#pragma unroll 2
  for (int c = 0; c < 512; ++c) {
    int i = c * 64 + lane;
    float X = px[i], Y = py[i], Z = pz[i], P = pp[i];
    float dot = fmaf(qz, Z, fmaf(qy, Y, __fmul_rn(qx, X)));       // fma-ascending
    float d2 = __fadd_rn(__fsub_rn(qq, __fadd_rn(dot, dot)), P);  // (qq - 2*dot) + pp
    unsigned u = __float_as_uint(d2);
    u ^= ((unsigned)(((int)u) >> 31)) | 0x80000000u;
    unsigned long long key = ((unsigned long long)u << 32) | (unsigned)i;
#pragma unroll
    for (int s = 0; s < 16; ++s) {
      unsigned long long lo = key < sl[s] ? key : sl[s];
      unsigned long long hi = key < sl[s] ? sl[s] : key;
      sl[s] = lo;
      key = hi;
    }
  }
#pragma unroll
  for (int s = 0; s < 16; ++s) mq[wid][s][lane] = sl[s];
  int head = 0;
  for (int r = 0; r < 16; ++r) {
    int hh = head < 16 ? head : 15;
    unsigned long long kk = mq[wid][hh][lane];
    if (head >= 16) kk = ~0ULL;
    unsigned long long v = kk;
#pragma unroll
    for (int off = 32; off; off >>= 1) {
      unsigned long long o = shfl_xor_u64(v, off);
      if (o < v) v = o;
    }
    if (kk == v) head++;
    if (lane == 0) nb[(size_t)q * 16 + r] = (int)(v & 0xffffffffULL);
  }
}

// ---------------- K5: gather + affine + relu + maxpool ----------------
__global__ __launch_bounds__(256) void k_gather(const float* __restrict__ h,
                                                const float* __restrict__ ss,
                                                const int* __restrict__ nb,
                                                float* __restrict__ y) {
  int t = threadIdx.x;
  int q = blockIdx.x * 2 + (t >> 7);
  int ch = t & 127;
  float sc = ss[ch], sh = ss[128 + ch];
  float m = -3.4e38f;
#pragma unroll
  for (int k = 0; k < 16; ++k) {
    int n = nb[(size_t)q * 16 + k];
    float v = h[(size_t)n * 128 + ch];
    m = fmaxf(m, fmaf(v, sc, sh));
  }
  y[(size_t)q * 128 + ch] = fmaxf(m, 0.0f);
}

extern "C" void kernel_launch(void* const* d_in, const int* in_sizes, int n_in,
                              void* d_out, int out_size, void* d_ws, size_t ws_size,
                              hipStream_t stream) {
  (void)in_sizes; (void)n_in; (void)out_size; (void)ws_size;
  const float* x = (const float*)d_in[0];
  const float* p1 = (const float*)d_in[1];
  const float* W = (const float*)d_in[2];
  const float* bias = (const float*)d_in[3];
  const float* gamma = (const float*)d_in[4];
  const float* beta = (const float*)d_in[5];

  float* out = (float*)d_out;
  float* y = out;                    // (8192,128)
  float* p2 = out + 1048576;         // (8192,3)

  // ws layout — identical footprint to R6/R8-proven:
  float* w = (float*)d_ws;
  float* h = w;                      // 4194304
  float* part = w + 4194304;         // 131072
  float* ss = w + 4325376;           // 256
  float* px = w + 4325632;           // 32768
  float* py = w + 4358400;
  float* pz = w + 4391168;
  float* pp = w + 4423936;
  int* nb = (int*)(w + 4456704);     // 8192*16 ints -> end 4489472 floats

  // FPS scratch in d_out's y-region (overwritten by k_gather at the very end):
  float4* pk = (float4*)y;           // 32768 float4 = 131072 floats
  int* cstart = (int*)(y + 131072);  // 513
  int* cursor = (int*)(y + 131648);  // 512   (end 132160 << 1048576)

  // md 32768 + wc 32 + winbuf 512 = 33312 floats = 133248 B
  const int fps_lds = 33312 * 4;
  hipFuncSetAttribute((const void*)k_fps6, hipFuncAttributeMaxDynamicSharedMemorySize, fps_lds);

  k_soa<<<128, 256, 0, stream>>>(p1, px, py, pz, pp);
  k_cells<<<1, 1024, 0, stream>>>(px, py, pz, cstart, cursor);
  k_scatter<<<128, 256, 0, stream>>>(px, py, pz, cursor, pk);
  k_mlp<<<512, 256, 0, stream>>>(x, W, bias, h, part);
  k_bn<<<1, 128, 0, stream>>>(part, gamma, beta, ss);
  k_fps6<<<1, 512, fps_lds, stream>>>(pk, cstart, p1, p2);
  k_knn<<<2048, 256, 0, stream>>>(px, py, pz, pp, p2, nb);
  k_gather<<<4096, 256, 0, stream>>>(h, ss, nb, y);
}

// Round 12
// 24036.771 us; speedup vs baseline: 2.3840x; 1.0090x over previous
//
#include <hip/hip_runtime.h>
#include <cstdint>
#include <cstddef>

// TransitionDown: FPS(8192 of 32768) + 16-NN + (Linear 64->128, BN, ReLU) + gather/maxpool
// R12: ONE-VARIABLE EXPERIMENT vs R11 — k_fps6 grid 1->256. Block 0 = byte-identical
// R11 FPS. Blocks 1..255 = FMA spinners (poll agent-scope flag, hard cap => no hang,
// write nothing => deterministic, 133KB LDS => 1 block/CU). Tests the DVFS hypothesis:
// consistent ~5x gap between latency models and measurements across R6/R9/R11 suggests
// a ~500MHz effective clock for a 1-CU workload; 255 busy CUs should pin boost clock.
// FROZEN numerics (R5-PASS, 7x verified): d = fmaf(dz,dz,fmaf(dy,dy,dx*dx)) with
// __fsub_rn subs; fminf(old,d); kNN dot fma-asc + qq/pp fma chains; ties -> lowest
// original index via unique packed key (oi<<16)|spos.

#define TD_N 32768
#define TD_M 8192

#define ROW_SHR1 0x111
#define ROW_SHR2 0x112
#define ROW_SHR4 0x114
#define ROW_SHR8 0x118
#define ROW_BCAST15 0x142
#define ROW_BCAST31 0x143

#define FOLD(V, P, NV, NP) \
  if ((NV) > (V) || ((NV) == (V) && (NP) < (P))) { (V) = (NV); (P) = (NP); }

// invalid-source lanes keep old value (bound_ctrl=false) => fold(self) = no-op
#define DPP_STEP(V, P, CTRL)                                                          \
  {                                                                                   \
    float nv_ = __int_as_float(__builtin_amdgcn_update_dpp(                           \
        __float_as_int(V), __float_as_int(V), CTRL, 0xF, 0xF, false));                \
    unsigned np_ = (unsigned)__builtin_amdgcn_update_dpp(                             \
        (int)(P), (int)(P), CTRL, 0xF, 0xF, false);                                   \
    FOLD(V, P, nv_, np_)                                                              \
  }

#define DPP_REDUCE64(V, P)                                                            \
  DPP_STEP(V, P, ROW_SHR1) DPP_STEP(V, P, ROW_SHR2) DPP_STEP(V, P, ROW_SHR4)          \
  DPP_STEP(V, P, ROW_SHR8) DPP_STEP(V, P, ROW_BCAST15) DPP_STEP(V, P, ROW_BCAST31)

__device__ __forceinline__ float sq3_fma(float a, float b, float c) {
  return fmaf(c, c, fmaf(b, b, __fmul_rn(a, a)));
}

__device__ __forceinline__ int cell_of(float x, float y, float z) {
  int ix = min(7, (int)(x * 8.0f));
  int iy = min(7, (int)(y * 8.0f));
  int iz = min(7, (int)(z * 8.0f));
  return (iz << 6) | (iy << 3) | ix;
}

// ---------------- K0: AoS -> SoA + |p|^2 (fma chain) ----------------
__global__ void k_soa(const float* __restrict__ p1, float* __restrict__ px,
                      float* __restrict__ py, float* __restrict__ pz,
                      float* __restrict__ pp) {
  int i = blockIdx.x * 256 + threadIdx.x;
  float a = p1[i * 3 + 0], b = p1[i * 3 + 1], c = p1[i * 3 + 2];
  px[i] = a; py[i] = b; pz[i] = c;
  pp[i] = sq3_fma(a, b, c);
}

// ---------------- K0b: histogram + prefix -> cell_start, cursor ----------------
__global__ __launch_bounds__(1024) void k_cells(const float* __restrict__ px,
                                                const float* __restrict__ py,
                                                const float* __restrict__ pz,
                                                int* __restrict__ cstart,
                                                int* __restrict__ cursor) {
  __shared__ int hist[512];
  __shared__ int wsum[16];
  int t = threadIdx.x;
  if (t < 512) hist[t] = 0;
  __syncthreads();
  for (int i = t; i < TD_N; i += 1024)
    atomicAdd(&hist[cell_of(px[i], py[i], pz[i])], 1);
  __syncthreads();
  int v = (t < 512) ? hist[t] : 0;
  int lane = t & 63, w = t >> 6;
  int s = v;
#pragma unroll
  for (int off = 1; off < 64; off <<= 1) {
    int o = __shfl_up(s, off);
    if (lane >= off) s += o;
  }
  if (lane == 63) wsum[w] = s;
  __syncthreads();
  if (t == 0) { int a = 0; for (int i = 0; i < 16; ++i) { int x = wsum[i]; wsum[i] = a; a += x; } }
  __syncthreads();
  int ex = s - v + wsum[w];
  if (t < 512) { cstart[t] = ex; cursor[t] = ex; }
  if (t == 0) cstart[512] = TD_N;
}

// ---------------- K0c: scatter into cell-sorted packed float4 ----------------
// Atomic order nondeterministic, but FPS outputs are order-invariant (elementwise
// min_d updates + unique-original-index tie-breaks).
__global__ __launch_bounds__(256) void k_scatter(const float* __restrict__ px,
                                                 const float* __restrict__ py,
                                                 const float* __restrict__ pz,
                                                 int* __restrict__ cursor,
                                                 float4* __restrict__ pk) {
  int i = blockIdx.x * 256 + threadIdx.x;
  float X = px[i], Y = py[i], Z = pz[i];
  int c = cell_of(X, Y, Z);
  int pos = atomicAdd(&cursor[c], 1);
  pk[pos] = make_float4(X, Y, Z, __int_as_float(i));
}

// ---------------- K0d: zero the spinner flag (replay-safe) ----------------
__global__ void k_flag0(int* __restrict__ flag) {
  if (threadIdx.x == 0) *flag = 0;
}

// ---------------- K1: h = x@W + b, + per-block BN partial sums ----------------
__global__ __launch_bounds__(256) void k_mlp(const float* __restrict__ x,
                                             const float* __restrict__ W,
                                             const float* __restrict__ bias,
                                             float* __restrict__ h,
                                             float* __restrict__ part) {
  __shared__ float Wl[64 * 128];
  __shared__ float pl[4][2][128];
  int t = threadIdx.x;
#pragma unroll
  for (int i = 0; i < 8; ++i) {
    int f4 = t + i * 256;
    ((float4*)Wl)[f4] = ((const float4*)W)[f4];
  }
  __syncthreads();

  int rg = t >> 4;
  int ch = (t & 15) * 8;
  int row0 = blockIdx.x * 64 + rg * 4;

  float acc[4][8];
#pragma unroll
  for (int r = 0; r < 4; ++r)
#pragma unroll
    for (int c = 0; c < 8; ++c) acc[r][c] = 0.f;

  const float* xrow = x + (size_t)row0 * 64;
#pragma unroll 4
  for (int kc = 0; kc < 16; ++kc) {
    float xv[4][4];
#pragma unroll
    for (int r = 0; r < 4; ++r) {
      float4 t4 = *(const float4*)(xrow + r * 64 + kc * 4);
      xv[r][0] = t4.x; xv[r][1] = t4.y; xv[r][2] = t4.z; xv[r][3] = t4.w;
    }
#pragma unroll
    for (int kk = 0; kk < 4; ++kk) {
      int k = kc * 4 + kk;
      float4 wa = *(const float4*)&Wl[k * 128 + ch];
      float4 wb = *(const float4*)&Wl[k * 128 + ch + 4];
      float wv[8] = {wa.x, wa.y, wa.z, wa.w, wb.x, wb.y, wb.z, wb.w};
#pragma unroll
      for (int r = 0; r < 4; ++r)
#pragma unroll
        for (int c = 0; c < 8; ++c) acc[r][c] = fmaf(xv[r][kk], wv[c], acc[r][c]);
    }
  }

  float bv[8];
#pragma unroll
  for (int c = 0; c < 8; ++c) bv[c] = bias[ch + c];
  float s[8], q2[8];
#pragma unroll
  for (int c = 0; c < 8; ++c) { s[c] = 0.f; q2[c] = 0.f; }
#pragma unroll
  for (int r = 0; r < 4; ++r) {
    float hv[8];
#pragma unroll
    for (int c = 0; c < 8; ++c) hv[c] = acc[r][c] + bv[c];
    *(float4*)&h[(size_t)(row0 + r) * 128 + ch] = make_float4(hv[0], hv[1], hv[2], hv[3]);
    *(float4*)&h[(size_t)(row0 + r) * 128 + ch + 4] = make_float4(hv[4], hv[5], hv[6], hv[7]);
#pragma unroll
    for (int c = 0; c < 8; ++c) { s[c] += hv[c]; q2[c] = fmaf(hv[c], hv[c], q2[c]); }
  }
#pragma unroll
  for (int off = 16; off <= 32; off <<= 1) {
#pragma unroll
    for (int c = 0; c < 8; ++c) {
      s[c] += __shfl_xor(s[c], off);
      q2[c] += __shfl_xor(q2[c], off);
    }
  }
  int wv_ = t >> 6;
  if ((t & 63) < 16) {
#pragma unroll
    for (int c = 0; c < 8; ++c) { pl[wv_][0][ch + c] = s[c]; pl[wv_][1][ch + c] = q2[c]; }
  }
  __syncthreads();
  if (t < 128) {
    float S = 0.f, Q = 0.f;
#pragma unroll
    for (int w = 0; w < 4; ++w) { S += pl[w][0][t]; Q += pl[w][1][t]; }
    part[(size_t)blockIdx.x * 256 + t] = S;
    part[(size_t)blockIdx.x * 256 + 128 + t] = Q;
  }
}

// ---------------- K2: finalize BN -> scale/shift ----------------
__global__ void k_bn(const float* __restrict__ part, const float* __restrict__ gamma,
                     const float* __restrict__ beta, float* __restrict__ ss) {
  int t = threadIdx.x;  // 128
  float S = 0.f, Q = 0.f;
  for (int b = 0; b < 512; ++b) {
    S += part[(size_t)b * 256 + t];
    Q += part[(size_t)b * 256 + 128 + t];
  }
  float mean = S * (1.0f / 32768.0f);
  float var = Q * (1.0f / 32768.0f) - mean * mean;
  var = fmaxf(var, 0.0f);
  float inv = 1.0f / sqrtf(var + 1e-5f);
  float sc = gamma[t] * inv;
  ss[t] = sc;
  ss[128 + t] = beta[t] - mean * sc;
}

// ---------------- K3: FPS block0 (byte-identical R11) + spinner blocks ----------------
__global__ __launch_bounds__(512) void k_fps6(const float4* __restrict__ pk,
                                              const int* __restrict__ cstart,
                                              const float* __restrict__ p1,
                                              float* __restrict__ p2,
                                              int* __restrict__ flag) {
  if (blockIdx.x != 0) {
    // spinner: keep this CU's VALU hot until block 0 completes (or hard cap).
    float a = 1.0f, b = 1.0000001f;
    for (int i = 0; i < 200000; ++i) {
#pragma unroll
      for (int j = 0; j < 512; ++j) a = fmaf(a, b, 1e-9f);
      if (__hip_atomic_load(flag, __ATOMIC_RELAXED, __HIP_MEMORY_SCOPE_AGENT)) break;
      if (a > 1e30f) a = 1.0f;  // keep finite
    }
    asm volatile("" ::"v"(a));  // keep the spin alive (no DCE)
    return;
  }

  extern __shared__ float lds[];
  float* md = lds;                                   // [32768]
  unsigned* wc = (unsigned*)(lds + 32768);           // [2][8][2] u32
  unsigned* winbuf = (unsigned*)(lds + 32768 + 32);  // [512] u32

  int t = threadIdx.x;
  int lane = t & 63, w = t >> 6;

  for (int i = t; i < TD_N; i += 512) md[i] = 1e10f;

  // my cell = w*64 + lane; bbox + range + seg-state ALL in registers
  int myc = (w << 6) | lane;
  int stR = cstart[myc], enR = cstart[myc + 1];
  stR = min(max(stR, 0), TD_N);
  enR = min(max(enR, stR), TD_N);
  float bx0 = 1e30f, bx1 = -1e30f, by0 = 1e30f, by1 = -1e30f, bz0 = 1e30f, bz1 = -1e30f;
  for (int p = stR; p < enR; ++p) {
    float4 v = pk[p];
    bx0 = fminf(bx0, v.x); bx1 = fmaxf(bx1, v.x);
    by0 = fminf(by0, v.y); by1 = fmaxf(by1, v.y);
    bz0 = fminf(bz0, v.z); bz1 = fmaxf(bz1, v.z);
  }
  float sv = (stR < enR) ? 1e10f : -1.0f;   // seg max value
  unsigned sp = 0xFFFFFFFFu;                // seg argmax packed (oi<<16)|spos
  float qx = p1[0], qy = p1[1], qz = p1[2];
  if (t == 0) { p2[0] = qx; p2[1] = qy; p2[2] = qz; }
  __syncthreads();

  for (int it = 1; it < TD_M; ++it) {
    // ---- prune my cell (registers only) ----
    float dxm = fmaxf(0.f, fmaxf(__fsub_rn(bx0, qx), __fsub_rn(qx, bx1)));
    float dym = fmaxf(0.f, fmaxf(__fsub_rn(by0, qy), __fsub_rn(qy, by1)));
    float dzm = fmaxf(0.f, fmaxf(__fsub_rn(bz0, qz), __fsub_rn(qz, bz1)));
    float lb2 = dxm * dxm + dym * dym + dzm * dzm;
    // safe-skip: lb2*(1-1e-5) >= segmax => no md in cell can change (chain err ~1e-6)
    bool dirty = !(lb2 * 0.99999f >= sv);
    float cv; unsigned cp;
    if (dirty) { cv = -2.0f; cp = 0xFFFFFFFFu; } else { cv = sv; cp = sp; }

    // ---- scan dirty cells (wave-uniform walk; DPP reduce per cell) ----
    unsigned long long mask = __ballot(dirty);
    while (mask) {
      int cl = (int)__builtin_ctzll(mask); mask &= mask - 1;
      int st = __builtin_amdgcn_readlane(stR, cl);
      int en = __builtin_amdgcn_readlane(enR, cl);
      float bv = -2.0f; unsigned bp = 0xFFFFFFFFu;
      for (int p0 = st; p0 < en; p0 += 64) {
        int p = p0 + lane;
        if (p < en) {
          float4 v = pk[p];
          float dx = __fsub_rn(v.x, qx);
          float dy = __fsub_rn(v.y, qy);
          float dz = __fsub_rn(v.z, qz);
          float d2 = fmaf(dz, dz, fmaf(dy, dy, __fmul_rn(dx, dx)));  // frozen chain
          float nm = fminf(md[p], d2);
          md[p] = nm;
          unsigned pkd = (((unsigned)__float_as_int(v.w)) << 16) | (unsigned)p;
          FOLD(bv, bp, nm, pkd)
        }
      }
      DPP_REDUCE64(bv, bp)
      float rbv = __int_as_float(__builtin_amdgcn_readlane(__float_as_int(bv), 63));
      unsigned rbp = (unsigned)__builtin_amdgcn_readlane((int)bp, 63);
      if (lane == cl) { sv = rbv; sp = rbp; }  // owner lane caches new seg state
      FOLD(cv, cp, rbv, rbp)
    }

    // ---- wave candidate -> LDS slot (parity-buffered), one barrier ----
    DPP_REDUCE64(cv, cp)
    if (lane == 63) {
      int par = (it & 1) << 4;
      wc[par + w * 2 + 0] = __float_as_uint(cv);
      wc[par + w * 2 + 1] = cp;
    }
    __syncthreads();

    // ---- all waves: fold 8 slots via DPP over lanes 0..7 ----
    unsigned gp;
    {
      int par = (it & 1) << 4;
      float v_; unsigned p_;
      if (lane < 8) {
        v_ = __uint_as_float(wc[par + lane * 2 + 0]);
        p_ = wc[par + lane * 2 + 1];
      } else { v_ = -2.0f; p_ = 0xFFFFFFFFu; }
      DPP_STEP(v_, p_, ROW_SHR1) DPP_STEP(v_, p_, ROW_SHR2) DPP_STEP(v_, p_, ROW_SHR4)
      gp = (unsigned)__builtin_amdgcn_readlane((int)p_, 7);
    }
    int spos = (int)(gp & 0xFFFFu);
    float4 wv = pk[spos];  // uniform address -> one L2 fetch per wave
    qx = wv.x; qy = wv.y; qz = wv.z;
    if (t == 0) winbuf[it & 511] = (unsigned)spos;

    // ---- flush p2 every 512 iterations (keeps global stores off the hot path) ----
    if ((it & 511) == 511) {
      __syncthreads();
      int j = it - 511 + t;
      if (j >= 1 && j <= it) {
        int sj = (int)winbuf[j & 511];
        float4 v = pk[sj];
        p2[(size_t)j * 3 + 0] = v.x;
        p2[(size_t)j * 3 + 1] = v.y;
        p2[(size_t)j * 3 + 2] = v.z;
      }
    }
  }
  __syncthreads();
  if (t == 0) __hip_atomic_store(flag, 1, __ATOMIC_RELEASE, __HIP_MEMORY_SCOPE_AGENT);
}

// ---------------- K4: 16-NN — expanded f32, all-FMA chains (frozen from R5) ----------------
__device__ __forceinline__ unsigned long long shfl_xor_u64(unsigned long long v, int m) {
  unsigned lo = __shfl_xor((unsigned)v, m);
  unsigned hi = __shfl_xor((unsigned)(v >> 32), m);
  return ((unsigned long long)hi << 32) | lo;
}

__global__ __launch_bounds__(256) void k_knn(const float* __restrict__ px,
                                             const float* __restrict__ py,
                                             const float* __restrict__ pz,
                                             const float* __restrict__ pp,
                                             const float* __restrict__ p2,
                                             int* __restrict__ nb) {
  __shared__ unsigned long long mq[4][16][64];
  int wid = threadIdx.x >> 6, lane = threadIdx.x & 63;
  int q = blockIdx.x * 4 + wid;
  float qx = p2[(size_t)q * 3 + 0], qy = p2[(size_t)q * 3 + 1], qz = p2[(size_t)q * 3 + 2];
  float qq = sq3_fma(qx, qy, qz);

  unsigned long long sl[16];
#pragma unroll
  for (int s = 0; s < 16; ++s) sl[s] = ~0ULL;

#pragma unroll 2
  for (int c = 0; c < 512; ++c) {
    int i = c * 64 + lane;
    float X = px[i], Y = py[i], Z = pz[i], P = pp[i];
    float dot = fmaf(qz, Z, fmaf(qy, Y, __fmul_rn(qx, X)));       // fma-ascending
    float d2 = __fadd_rn(__fsub_rn(qq, __fadd_rn(dot, dot)), P);  // (qq - 2*dot) + pp
    unsigned u = __float_as_uint(d2);
    u ^= ((unsigned)(((int)u) >> 31)) | 0x80000000u;
    unsigned long long key = ((unsigned long long)u << 32) | (unsigned)i;
#pragma unroll
    for (int s = 0; s < 16; ++s) {
      unsigned long long lo = key < sl[s] ? key : sl[s];
      unsigned long long hi = key < sl[s] ? sl[s] : key;
      sl[s] = lo;
      key = hi;
    }
  }
#pragma unroll
  for (int s = 0; s < 16; ++s) mq[wid][s][lane] = sl[s];
  int head = 0;
  for (int r = 0; r < 16; ++r) {
    int hh = head < 16 ? head : 15;
    unsigned long long kk = mq[wid][hh][lane];
    if (head >= 16) kk = ~0ULL;
    unsigned long long v = kk;
#pragma unroll
    for (int off = 32; off; off >>= 1) {
      unsigned long long o = shfl_xor_u64(v, off);
      if (o < v) v = o;
    }
    if (kk == v) head++;
    if (lane == 0) nb[(size_t)q * 16 + r] = (int)(v & 0xffffffffULL);
  }
}

// ---------------- K5: gather + affine + relu + maxpool ----------------
__global__ __launch_bounds__(256) void k_gather(const float* __restrict__ h,
                                                const float* __restrict__ ss,
                                                const int* __restrict__ nb,
                                                float* __restrict__ y) {
  int t = threadIdx.x;
  int q = blockIdx.x * 2 + (t >> 7);
  int ch = t & 127;
  float sc = ss[ch], sh = ss[128 + ch];
  float m = -3.4e38f;
#pragma unroll
  for (int k = 0; k < 16; ++k) {
    int n = nb[(size_t)q * 16 + k];
    float v = h[(size_t)n * 128 + ch];
    m = fmaxf(m, fmaf(v, sc, sh));
  }
  y[(size_t)q * 128 + ch] = fmaxf(m, 0.0f);
}

extern "C" void kernel_launch(void* const* d_in, const int* in_sizes, int n_in,
                              void* d_out, int out_size, void* d_ws, size_t ws_size,
                              hipStream_t stream) {
  (void)in_sizes; (void)n_in; (void)out_size; (void)ws_size;
  const float* x = (const float*)d_in[0];
  const float* p1 = (const float*)d_in[1];
  const float* W = (const float*)d_in[2];
  const float* bias = (const float*)d_in[3];
  const float* gamma = (const float*)d_in[4];
  const float* beta = (const float*)d_in[5];

  float* out = (float*)d_out;
  float* y = out;                    // (8192,128)
  float* p2 = out + 1048576;         // (8192,3)

  // ws layout — identical footprint to R6/R8-proven:
  float* w = (float*)d_ws;
  float* h = w;                      // 4194304
  float* part = w + 4194304;         // 131072
  float* ss = w + 4325376;           // 256
  float* px = w + 4325632;           // 32768
  float* py = w + 4358400;
  float* pz = w + 4391168;
  float* pp = w + 4423936;
  int* nb = (int*)(w + 4456704);     // 8192*16 ints -> end 4489472 floats

  // FPS scratch in d_out's y-region (overwritten by k_gather at the very end):
  float4* pk = (float4*)y;           // 32768 float4 = 131072 floats
  int* cstart = (int*)(y + 131072);  // 513
  int* cursor = (int*)(y + 131648);  // 512
  int* flag = (int*)(y + 132160);    // 1     (end 132161 << 1048576)

  // md 32768 + wc 32 + winbuf 512 = 33312 floats = 133248 B
  const int fps_lds = 33312 * 4;
  hipFuncSetAttribute((const void*)k_fps6, hipFuncAttributeMaxDynamicSharedMemorySize, fps_lds);

  k_soa<<<128, 256, 0, stream>>>(p1, px, py, pz, pp);
  k_cells<<<1, 1024, 0, stream>>>(px, py, pz, cstart, cursor);
  k_scatter<<<128, 256, 0, stream>>>(px, py, pz, cursor, pk);
  k_mlp<<<512, 256, 0, stream>>>(x, W, bias, h, part);
  k_bn<<<1, 128, 0, stream>>>(part, gamma, beta, ss);
  k_flag0<<<1, 64, 0, stream>>>(flag);
  k_fps6<<<256, 512, fps_lds, stream>>>(pk, cstart, p1, p2, flag);
  k_knn<<<2048, 256, 0, stream>>>(px, py, pz, pp, p2, nb);
  k_gather<<<4096, 256, 0, stream>>>(h, ss, nb, y);
}

// Round 13
// 21969.366 us; speedup vs baseline: 2.6084x; 1.0941x over previous
//
#include <hip/hip_runtime.h>
#include <cstdint>
#include <cstddef>

// TransitionDown: FPS(8192 of 32768) + 16-NN + (Linear 64->128, BN, ReLU) + gather/maxpool
// R13: k_fps7 — zero global ops in the hot loop. u64 sortable key (bits(md)<<32)|~pkd;
// winner COORDS carried through DPP reduces (no pk[spos] HBM fetch — R12 FETCH_SIZE
// showed ~1 HBM line/iter = the winner fetch); raw s_barrier + lgkmcnt(0) (no vmcnt
// drain); parity slots; p2 via LDS winbuf flushed every 512 iters.
// FROZEN numerics (R5-PASS, 8x verified): d = fmaf(dz,dz,fmaf(dy,dy,dx*dx)) with
// __fsub_rn subs; fminf(old,d); kNN dot fma-asc + qq/pp fma chains; ties -> lowest
// original index via packed pkd=(oi<<16)|spos (key order == (val desc, pkd asc)).

#define TD_N 32768
#define TD_M 8192

#define ROW_SHR1 0x111
#define ROW_SHR2 0x112
#define ROW_SHR4 0x114
#define ROW_SHR8 0x118
#define ROW_BCAST15 0x142
#define ROW_BCAST31 0x143

// 5-chain DPP fold step: (keyH,keyL) u64 max, coords follow the winner.
// bound_ctrl=false: invalid-source lanes keep old value => fold(self) = no-op.
#define DPP5_STEP(KH, KL, X, Y, Z, CTRL)                                              \
  {                                                                                   \
    unsigned nh_ = (unsigned)__builtin_amdgcn_update_dpp((int)(KH), (int)(KH), CTRL, 0xF, 0xF, false); \
    unsigned nl_ = (unsigned)__builtin_amdgcn_update_dpp((int)(KL), (int)(KL), CTRL, 0xF, 0xF, false); \
    int nx_ = __builtin_amdgcn_update_dpp(__float_as_int(X), __float_as_int(X), CTRL, 0xF, 0xF, false); \
    int ny_ = __builtin_amdgcn_update_dpp(__float_as_int(Y), __float_as_int(Y), CTRL, 0xF, 0xF, false); \
    int nz_ = __builtin_amdgcn_update_dpp(__float_as_int(Z), __float_as_int(Z), CTRL, 0xF, 0xF, false); \
    unsigned long long a_ = (((unsigned long long)(KH)) << 32) | (unsigned long long)(KL); \
    unsigned long long b_ = (((unsigned long long)nh_) << 32) | (unsigned long long)nl_;   \
    if (b_ > a_) { KH = nh_; KL = nl_; X = __int_as_float(nx_); Y = __int_as_float(ny_); Z = __int_as_float(nz_); } \
  }

#define DPP5_REDUCE64(KH, KL, X, Y, Z)                                                \
  DPP5_STEP(KH, KL, X, Y, Z, ROW_SHR1) DPP5_STEP(KH, KL, X, Y, Z, ROW_SHR2)           \
  DPP5_STEP(KH, KL, X, Y, Z, ROW_SHR4) DPP5_STEP(KH, KL, X, Y, Z, ROW_SHR8)           \
  DPP5_STEP(KH, KL, X, Y, Z, ROW_BCAST15) DPP5_STEP(KH, KL, X, Y, Z, ROW_BCAST31)

// hot-loop barrier: only LDS needs draining (no global ops in steady state)
#define HOT_BARRIER()                                           \
  {                                                             \
    asm volatile("s_waitcnt lgkmcnt(0)" ::: "memory");          \
    __builtin_amdgcn_s_barrier();                               \
    __builtin_amdgcn_sched_barrier(0);                          \
    asm volatile("" ::: "memory");                              \
  }

__device__ __forceinline__ float sq3_fma(float a, float b, float c) {
  return fmaf(c, c, fmaf(b, b, __fmul_rn(a, a)));
}

__device__ __forceinline__ int cell_of(float x, float y, float z) {
  int ix = min(7, (int)(x * 8.0f));
  int iy = min(7, (int)(y * 8.0f));
  int iz = min(7, (int)(z * 8.0f));
  return (iz << 6) | (iy << 3) | ix;
}

// ---------------- K0: AoS -> SoA + |p|^2 (fma chain) ----------------
__global__ void k_soa(const float* __restrict__ p1, float* __restrict__ px,
                      float* __restrict__ py, float* __restrict__ pz,
                      float* __restrict__ pp) {
  int i = blockIdx.x * 256 + threadIdx.x;
  float a = p1[i * 3 + 0], b = p1[i * 3 + 1], c = p1[i * 3 + 2];
  px[i] = a; py[i] = b; pz[i] = c;
  pp[i] = sq3_fma(a, b, c);
}

// ---------------- K0b: histogram + prefix -> cell_start, cursor ----------------
__global__ __launch_bounds__(1024) void k_cells(const float* __restrict__ px,
                                                const float* __restrict__ py,
                                                const float* __restrict__ pz,
                                                int* __restrict__ cstart,
                                                int* __restrict__ cursor) {
  __shared__ int hist[512];
  __shared__ int wsum[16];
  int t = threadIdx.x;
  if (t < 512) hist[t] = 0;
  __syncthreads();
  for (int i = t; i < TD_N; i += 1024)
    atomicAdd(&hist[cell_of(px[i], py[i], pz[i])], 1);
  __syncthreads();
  int v = (t < 512) ? hist[t] : 0;
  int lane = t & 63, w = t >> 6;
  int s = v;
#pragma unroll
  for (int off = 1; off < 64; off <<= 1) {
    int o = __shfl_up(s, off);
    if (lane >= off) s += o;
  }
  if (lane == 63) wsum[w] = s;
  __syncthreads();
  if (t == 0) { int a = 0; for (int i = 0; i < 16; ++i) { int x = wsum[i]; wsum[i] = a; a += x; } }
  __syncthreads();
  int ex = s - v + wsum[w];
  if (t < 512) { cstart[t] = ex; cursor[t] = ex; }
  if (t == 0) cstart[512] = TD_N;
}

// ---------------- K0c: scatter into cell-sorted packed float4 ----------------
// Atomic order nondeterministic, but FPS outputs are order-invariant (elementwise
// min_d updates + unique-original-index tie-breaks).
__global__ __launch_bounds__(256) void k_scatter(const float* __restrict__ px,
                                                 const float* __restrict__ py,
                                                 const float* __restrict__ pz,
                                                 int* __restrict__ cursor,
                                                 float4* __restrict__ pk) {
  int i = blockIdx.x * 256 + threadIdx.x;
  float X = px[i], Y = py[i], Z = pz[i];
  int c = cell_of(X, Y, Z);
  int pos = atomicAdd(&cursor[c], 1);
  pk[pos] = make_float4(X, Y, Z, __int_as_float(i));
}

// ---------------- K1: h = x@W + b, + per-block BN partial sums ----------------
__global__ __launch_bounds__(256) void k_mlp(const float* __restrict__ x,
                                             const float* __restrict__ W,
                                             const float* __restrict__ bias,
                                             float* __restrict__ h,
                                             float* __restrict__ part) {
  __shared__ float Wl[64 * 128];
  __shared__ float pl[4][2][128];
  int t = threadIdx.x;
#pragma unroll
  for (int i = 0; i < 8; ++i) {
    int f4 = t + i * 256;
    ((float4*)Wl)[f4] = ((const float4*)W)[f4];
  }
  __syncthreads();

  int rg = t >> 4;
  int ch = (t & 15) * 8;
  int row0 = blockIdx.x * 64 + rg * 4;

  float acc[4][8];
#pragma unroll
  for (int r = 0; r < 4; ++r)
#pragma unroll
    for (int c = 0; c < 8; ++c) acc[r][c] = 0.f;

  const float* xrow = x + (size_t)row0 * 64;
#pragma unroll 4
  for (int kc = 0; kc < 16; ++kc) {
    float xv[4][4];
#pragma unroll
    for (int r = 0; r < 4; ++r) {
      float4 t4 = *(const float4*)(xrow + r * 64 + kc * 4);
      xv[r][0] = t4.x; xv[r][1] = t4.y; xv[r][2] = t4.z; xv[r][3] = t4.w;
    }
#pragma unroll
    for (int kk = 0; kk < 4; ++kk) {
      int k = kc * 4 + kk;
      float4 wa = *(const float4*)&Wl[k * 128 + ch];
      float4 wb = *(const float4*)&Wl[k * 128 + ch + 4];
      float wv[8] = {wa.x, wa.y, wa.z, wa.w, wb.x, wb.y, wb.z, wb.w};
#pragma unroll
      for (int r = 0; r < 4; ++r)
#pragma unroll
        for (int c = 0; c < 8; ++c) acc[r][c] = fmaf(xv[r][kk], wv[c], acc[r][c]);
    }
  }

  float bv[8];
#pragma unroll
  for (int c = 0; c < 8; ++c) bv[c] = bias[ch + c];
  float s[8], q2[8];
#pragma unroll
  for (int c = 0; c < 8; ++c) { s[c] = 0.f; q2[c] = 0.f; }
#pragma unroll
  for (int r = 0; r < 4; ++r) {
    float hv[8];
#pragma unroll
    for (int c = 0; c < 8; ++c) hv[c] = acc[r][c] + bv[c];
    *(float4*)&h[(size_t)(row0 + r) * 128 + ch] = make_float4(hv[0], hv[1], hv[2], hv[3]);
    *(float4*)&h[(size_t)(row0 + r) * 128 + ch + 4] = make_float4(hv[4], hv[5], hv[6], hv[7]);
#pragma unroll
    for (int c = 0; c < 8; ++c) { s[c] += hv[c]; q2[c] = fmaf(hv[c], hv[c], q2[c]); }
  }
#pragma unroll
  for (int off = 16; off <= 32; off <<= 1) {
#pragma unroll
    for (int c = 0; c < 8; ++c) {
      s[c] += __shfl_xor(s[c], off);
      q2[c] += __shfl_xor(q2[c], off);
    }
  }
  int wv_ = t >> 6;
  if ((t & 63) < 16) {
#pragma unroll
    for (int c = 0; c < 8; ++c) { pl[wv_][0][ch + c] = s[c]; pl[wv_][1][ch + c] = q2[c]; }
  }
  __syncthreads();
  if (t < 128) {
    float S = 0.f, Q = 0.f;
#pragma unroll
    for (int w = 0; w < 4; ++w) { S += pl[w][0][t]; Q += pl[w][1][t]; }
    part[(size_t)blockIdx.x * 256 + t] = S;
    part[(size_t)blockIdx.x * 256 + 128 + t] = Q;
  }
}

// ---------------- K2: finalize BN -> scale/shift ----------------
__global__ void k_bn(const float* __restrict__ part, const float* __restrict__ gamma,
                     const float* __restrict__ beta, float* __restrict__ ss) {
  int t = threadIdx.x;  // 128
  float S = 0.f, Q = 0.f;
  for (int b = 0; b < 512; ++b) {
    S += part[(size_t)b * 256 + t];
    Q += part[(size_t)b * 256 + 128 + t];
  }
  float mean = S * (1.0f / 32768.0f);
  float var = Q * (1.0f / 32768.0f) - mean * mean;
  var = fmaxf(var, 0.0f);
  float inv = 1.0f / sqrtf(var + 1e-5f);
  float sc = gamma[t] * inv;
  ss[t] = sc;
  ss[128 + t] = beta[t] - mean * sc;
}

// ---------------- K3: FPS — 512 thr, coords-through-reduce, no global ops in loop ----------------
__global__ __launch_bounds__(512) void k_fps7(const float4* __restrict__ pk,
                                              const int* __restrict__ cstart,
                                              const float* __restrict__ p1,
                                              float* __restrict__ p2) {
  extern __shared__ float lds[];
  float* md = lds;                              // [32768]
  unsigned* wc = (unsigned*)(lds + 32768);      // [2][8][8] u32 (parity, wave, 5 used)
  float* winbuf = lds + 32768 + 128;            // [512][3]

  int t = threadIdx.x;
  int lane = t & 63, w = t >> 6;

  for (int i = t; i < TD_N; i += 512) md[i] = 1e10f;

  // my cell = w*64 + lane; bbox + range + seg-state (val,pkd,coords) ALL in registers
  int myc = (w << 6) | lane;
  int stR = cstart[myc], enR = cstart[myc + 1];
  stR = min(max(stR, 0), TD_N);
  enR = min(max(enR, stR), TD_N);
  float bx0 = 1e30f, bx1 = -1e30f, by0 = 1e30f, by1 = -1e30f, bz0 = 1e30f, bz1 = -1e30f;
  for (int p = stR; p < enR; ++p) {
    float4 v = pk[p];
    bx0 = fminf(bx0, v.x); bx1 = fmaxf(bx1, v.x);
    by0 = fminf(by0, v.y); by1 = fmaxf(by1, v.y);
    bz0 = fminf(bz0, v.z); bz1 = fmaxf(bz1, v.z);
  }
  bool nonempty = (stR < enR);
  float sv = nonempty ? 1e10f : -1.0f;  // seg max value (float for prune compare)
  unsigned spk = 0xFFFFFFFFu;           // seg argmax pkd
  float sx = 0.f, sy = 0.f, sz = 0.f;   // seg argmax coords (valid after first scan;
                                        // iter 1 scans every non-empty cell)
  float qx = p1[0], qy = p1[1], qz = p1[2];
  if (t == 0) { p2[0] = qx; p2[1] = qy; p2[2] = qz; }
  __syncthreads();

  for (int it = 1; it < TD_M; ++it) {
    // ---- prune my cell (registers only) ----
    float dxm = fmaxf(0.f, fmaxf(__fsub_rn(bx0, qx), __fsub_rn(qx, bx1)));
    float dym = fmaxf(0.f, fmaxf(__fsub_rn(by0, qy), __fsub_rn(qy, by1)));
    float dzm = fmaxf(0.f, fmaxf(__fsub_rn(bz0, qz), __fsub_rn(qz, bz1)));
    float lb2 = dxm * dxm + dym * dym + dzm * dzm;
    // safe-skip: lb2*(1-1e-5) >= segmax => no md in cell can change (chain err ~1e-6)
    bool dirty = !(lb2 * 0.99999f >= sv);

    // ---- scan dirty cells of my wave; coords ride the per-cell DPP reduce ----
    unsigned long long mask = __ballot(dirty);
    while (mask) {
      int cl = (int)__builtin_ctzll(mask); mask &= mask - 1;
      int st = __builtin_amdgcn_readlane(stR, cl);
      int en = __builtin_amdgcn_readlane(enR, cl);
      unsigned bh = 0u, bl = 0u;       // key sentinel 0 loses to any real candidate
      float bx = 0.f, by = 0.f, bz = 0.f;
      for (int p0 = st; p0 < en; p0 += 64) {
        int p = p0 + lane;
        if (p < en) {
          float4 v = pk[p];
          float dx = __fsub_rn(v.x, qx);
          float dy = __fsub_rn(v.y, qy);
          float dz = __fsub_rn(v.z, qz);
          float d2 = fmaf(dz, dz, fmaf(dy, dy, __fmul_rn(dx, dx)));  // frozen chain
          float nm = fminf(md[p], d2);
          md[p] = nm;
          unsigned pkd = (((unsigned)__float_as_int(v.w)) << 16) | (unsigned)p;
          unsigned kh = __float_as_uint(nm);   // nm >= 0 => bit order == value order
          unsigned kl = ~pkd;                  // tie: max ~pkd == min pkd
          unsigned long long a = (((unsigned long long)bh) << 32) | bl;
          unsigned long long b = (((unsigned long long)kh) << 32) | kl;
          if (b > a) { bh = kh; bl = kl; bx = v.x; by = v.y; bz = v.z; }
        }
      }
      DPP5_REDUCE64(bh, bl, bx, by, bz)
      unsigned rh = (unsigned)__builtin_amdgcn_readlane((int)bh, 63);
      unsigned rl = (unsigned)__builtin_amdgcn_readlane((int)bl, 63);
      int rx = __builtin_amdgcn_readlane(__float_as_int(bx), 63);
      int ry = __builtin_amdgcn_readlane(__float_as_int(by), 63);
      int rz = __builtin_amdgcn_readlane(__float_as_int(bz), 63);
      if (lane == cl) {  // owner lane caches new seg state
        sv = __uint_as_float(rh);
        spk = ~rl;
        sx = __int_as_float(rx); sy = __int_as_float(ry); sz = __int_as_float(rz);
      }
    }

    // ---- wave candidate = per-lane seg state, ONE DPP reduce ----
    unsigned ch_, cl_;
    if (nonempty) { ch_ = __float_as_uint(sv); cl_ = ~spk; } else { ch_ = 0u; cl_ = 0u; }
    float cx_ = sx, cy_ = sy, cz_ = sz;
    DPP5_REDUCE64(ch_, cl_, cx_, cy_, cz_)
    if (lane == 63) {
      unsigned* slot = &wc[((it & 1) << 6) + (w << 3)];
      slot[0] = ch_; slot[1] = cl_;
      slot[2] = __float_as_uint(cx_); slot[3] = __float_as_uint(cy_); slot[4] = __float_as_uint(cz_);
    }
    HOT_BARRIER()

    // ---- all waves: fold 8 slots (lanes 0..7), 3 DPP steps, winner in lane 7 ----
    {
      unsigned gh = 0u, gl = 0u; float gx = 0.f, gy = 0.f, gz = 0.f;
      if (lane < 8) {
        unsigned* slot = &wc[((it & 1) << 6) + (lane << 3)];
        gh = slot[0]; gl = slot[1];
        gx = __uint_as_float(slot[2]); gy = __uint_as_float(slot[3]); gz = __uint_as_float(slot[4]);
      }
      DPP5_STEP(gh, gl, gx, gy, gz, ROW_SHR1)
      DPP5_STEP(gh, gl, gx, gy, gz, ROW_SHR2)
      DPP5_STEP(gh, gl, gx, gy, gz, ROW_SHR4)
      qx = __int_as_float(__builtin_amdgcn_readlane(__float_as_int(gx), 7));
      qy = __int_as_float(__builtin_amdgcn_readlane(__float_as_int(gy), 7));
      qz = __int_as_float(__builtin_amdgcn_readlane(__float_as_int(gz), 7));
    }
    if (t == 0) {
      int s0 = (it & 511) * 3;
      winbuf[s0 + 0] = qx; winbuf[s0 + 1] = qy; winbuf[s0 + 2] = qz;
    }

    // ---- flush p2 every 512 iterations (global stores off the hot path) ----
    if ((it & 511) == 511) {
      __syncthreads();
      int j = it - 511 + t;
      if (j >= 1 && j <= it) {
        int s0 = (j & 511) * 3;
        p2[(size_t)j * 3 + 0] = winbuf[s0 + 0];
        p2[(size_t)j * 3 + 1] = winbuf[s0 + 1];
        p2[(size_t)j * 3 + 2] = winbuf[s0 + 2];
      }
      __syncthreads();
    }
  }
}

// ---------------- K4: 16-NN — expanded f32, all-FMA chains (frozen from R5) ----------------
__device__ __forceinline__ unsigned long long shfl_xor_u64(unsigned long long v, int m) {
  unsigned lo = __shfl_xor((unsigned)v, m);
  unsigned hi = __shfl_xor((unsigned)(v >> 32), m);
  return ((unsigned long long)hi << 32) | lo;
}

__global__ __launch_bounds__(256) void k_knn(const float* __restrict__ px,
                                             const float* __restrict__ py,
                                             const float* __restrict__ pz,
                                             const float* __restrict__ pp,
                                             const float* __restrict__ p2,
                                             int* __restrict__ nb) {
  __shared__ unsigned long long mq[4][16][64];
  int wid = threadIdx.x >> 6, lane = threadIdx.x & 63;
  int q = blockIdx.x * 4 + wid;
  float qx = p2[(size_t)q * 3 + 0], qy = p2[(size_t)q * 3 + 1], qz = p2[(size_t)q * 3 + 2];
  float qq = sq3_fma(qx, qy, qz);

  unsigned long long sl[16];
#pragma unroll
  for (int s = 0; s < 16; ++s) sl[s] = ~0ULL;

#pragma unroll 2
  for (int c = 0; c < 512; ++c) {
    int i = c * 64 + lane;
    float X = px[i], Y = py[i], Z = pz[i], P = pp[i];
    float dot = fmaf(qz, Z, fmaf(qy, Y, __fmul_rn(qx, X)));       // fma-ascending
    float d2 = __fadd_rn(__fsub_rn(qq, __fadd_rn(dot, dot)), P);  // (qq - 2*dot) + pp
    unsigned u = __float_as_uint(d2);
    u ^= ((unsigned)(((int)u) >> 31)) | 0x80000000u;
    unsigned long long key = ((unsigned long long)u << 32) | (unsigned)i;
#pragma unroll
    for (int s = 0; s < 16; ++s) {
      unsigned long long lo = key < sl[s] ? key : sl[s];
      unsigned long long hi = key < sl[s] ? sl[s] : key;
      sl[s] = lo;
      key = hi;
    }
  }
#pragma unroll
  for (int s = 0; s < 16; ++s) mq[wid][s][lane] = sl[s];
  int head = 0;
  for (int r = 0; r < 16; ++r) {
    int hh = head < 16 ? head : 15;
    unsigned long long kk = mq[wid][hh][lane];
    if (head >= 16) kk = ~0ULL;
    unsigned long long v = kk;
#pragma unroll
    for (int off = 32; off; off >>= 1) {
      unsigned long long o = shfl_xor_u64(v, off);
      if (o < v) v = o;
    }
    if (kk == v) head++;
    if (lane == 0) nb[(size_t)q * 16 + r] = (int)(v & 0xffffffffULL);
  }
}

// ---------------- K5: gather + affine + relu + maxpool ----------------
__global__ __launch_bounds__(256) void k_gather(const float* __restrict__ h,
                                                const float* __restrict__ ss,
                                                const int* __restrict__ nb,
                                                float* __restrict__ y) {
  int t = threadIdx.x;
  int q = blockIdx.x * 2 + (t >> 7);
  int ch = t & 127;
  float sc = ss[ch], sh = ss[128 + ch];
  float m = -3.4e38f;
#pragma unroll
  for (int k = 0; k < 16; ++k) {
    int n = nb[(size_t)q * 16 + k];
    float v = h[(size_t)n * 128 + ch];
    m = fmaxf(m, fmaf(v, sc, sh));
  }
  y[(size_t)q * 128 + ch] = fmaxf(m, 0.0f);
}

extern "C" void kernel_launch(void* const* d_in, const int* in_sizes, int n_in,
                              void* d_out, int out_size, void* d_ws, size_t ws_size,
                              hipStream_t stream) {
  (void)in_sizes; (void)n_in; (void)out_size; (void)ws_size;
  const float* x = (const float*)d_in[0];
  const float* p1 = (const float*)d_in[1];
  const float* W = (const float*)d_in[2];
  const float* bias = (const float*)d_in[3];
  const float* gamma = (const float*)d_in[4];
  const float* beta = (const float*)d_in[5];

  float* out = (float*)d_out;
  float* y = out;                    // (8192,128)
  float* p2 = out + 1048576;         // (8192,3)

  // ws layout — identical footprint to R6/R8-proven:
  float* w = (float*)d_ws;
  float* h = w;                      // 4194304
  float* part = w + 4194304;         // 131072
  float* ss = w + 4325376;           // 256
  float* px = w + 4325632;           // 32768
  float* py = w + 4358400;
  float* pz = w + 4391168;
  float* pp = w + 4423936;
  int* nb = (int*)(w + 4456704);     // 8192*16 ints -> end 4489472 floats

  // FPS scratch in d_out's y-region (overwritten by k_gather at the very end):
  float4* pk = (float4*)y;           // 32768 float4 = 131072 floats
  int* cstart = (int*)(y + 131072);  // 513
  int* cursor = (int*)(y + 131648);  // 512   (end 132160 << 1048576)

  // md 32768 + wc 128 + winbuf 1536 = 34432 floats = 137728 B
  const int fps_lds = 34432 * 4;
  hipFuncSetAttribute((const void*)k_fps7, hipFuncAttributeMaxDynamicSharedMemorySize, fps_lds);

  k_soa<<<128, 256, 0, stream>>>(p1, px, py, pz, pp);
  k_cells<<<1, 1024, 0, stream>>>(px, py, pz, cstart, cursor);
  k_scatter<<<128, 256, 0, stream>>>(px, py, pz, cursor, pk);
  k_mlp<<<512, 256, 0, stream>>>(x, W, bias, h, part);
  k_bn<<<1, 128, 0, stream>>>(part, gamma, beta, ss);
  k_fps7<<<1, 512, fps_lds, stream>>>(pk, cstart, p1, p2);
  k_knn<<<2048, 256, 0, stream>>>(px, py, pz, pp, p2, nb);
  k_gather<<<4096, 256, 0, stream>>>(h, ss, nb, y);
}